// Round 13
// baseline (5336.264 us; speedup 1.0000x reference)
//
#include <hip/hip_runtime.h>
#include <hip/hip_bf16.h>
#include <math.h>

// ---- problem constants ----
#define BB 4
#define NTOK 4096
#define KCB 8192
#define ED 16

__device__ __forceinline__ float silu_f(float x){ return x / (1.0f + expf(-x)); }
__device__ __forceinline__ double silu_d(double x){ return x / (1.0 + exp(-x)); }

template<typename T> struct V4T { typedef T type __attribute__((ext_vector_type(4))); };
typedef float f2v __attribute__((ext_vector_type(2)));

// ================= input dtype probe: block-reduced flags =================
__global__ void r9_probe_zero(int* flags){ if (threadIdx.x < 2) flags[threadIdx.x] = 0; }

__global__ void r17_probe(const unsigned char* __restrict__ x, int* __restrict__ flags){
  __shared__ int so, sa;
  if (threadIdx.x == 0){ so = 0; sa = 0; }
  __syncthreads();
  const uint4* p = (const uint4*)x + (size_t)(blockIdx.x*256 + threadIdx.x)*4;
  unsigned uo = 0, ua = 0;
  #pragma unroll
  for (int r=0;r<4;++r){
    uint4 v = p[r];
    unsigned uw = v.x | v.y | v.z | v.w;
    uo |= (uw & 0xFFFFFF00u);
    ua |= (uw & 0x000000FFu);
  }
  if (uo) so = 1;
  if (ua) sa = 1;
  __syncthreads();
  if (threadIdx.x == 0){
    if (so) atomicOr(flags + 0, 1);
    if (sa) atomicOr(flags + 1, 1);
  }
}

// ================= pack bool -> multichannel (dtype-adaptive) =================
__global__ void r9_pack_mc(const unsigned char* __restrict__ x, float* __restrict__ mc,
                           const int* __restrict__ flags){
  int t = blockIdx.x*256 + threadIdx.x;          // B*64^3
  int k = t & 63, j = (t>>6)&63, i = (t>>12)&63, b = t>>18;
  int is_i32 = (flags[1] != 0) && (flags[0] == 0);
  unsigned ch[8];
  #pragma unroll
  for (int q=0;q<8;++q) ch[q]=0u;
  if (is_i32){
    const int* xb = (const int*)x + ((size_t)b << 24);
    #pragma unroll
    for (int a=0;a<4;++a){
      #pragma unroll
      for (int b2=0;b2<4;++b2){
        const int4 v = *(const int4*)(xb + (((size_t)(4*i+a))<<16) + ((size_t)(4*j+b2)<<8) + (size_t)(4*k));
        int vv[4] = {v.x, v.y, v.z, v.w};
        #pragma unroll
        for (int c2=0;c2<4;++c2){
          int lin = a*16 + b2*4 + c2;
          unsigned bit = vv[c2] ? 1u : 0u;
          ch[lin>>3] += bit << (lin&7);
        }
      }
    }
  } else {
    const unsigned char* xb = x + ((size_t)b << 24);
    #pragma unroll
    for (int a=0;a<4;++a){
      #pragma unroll
      for (int b2=0;b2<4;++b2){
        const unsigned char* row = xb + (((size_t)(4*i+a))<<16) + ((size_t)(4*j+b2)<<8) + (size_t)(4*k);
        unsigned v = *(const unsigned*)row;
        #pragma unroll
        for (int c2=0;c2<4;++c2){
          int lin = a*16 + b2*4 + c2;
          unsigned bit = ((v >> (8*c2)) & 0xffu) ? 1u : 0u;
          ch[lin>>3] += bit << (lin&7);
        }
      }
    }
  }
  size_t sp = ((size_t)i<<12) + (j<<6) + k;
  #pragma unroll
  for (int q=0;q<8;++q)
    mc[(((size_t)(b*8+q))<<18) + sp] = (float)ch[q] / 255.0f;
}

__global__ void r9_token_nz(const float* __restrict__ mc, unsigned char* __restrict__ tnz){
  int t = blockIdx.x*64 + threadIdx.x;   // 16384
  int tk = t&15, tj=(t>>4)&15, ti=(t>>8)&15, b=t>>12;
  bool any = false;
  for (int q=0;q<8 && !any;++q){
    const float* mq = mc + (((size_t)(b*8+q))<<18);
    for (int a=0;a<4;++a)
      for (int c=0;c<4;++c){
        const float4 v = *(const float4*)(mq + ((size_t)(4*ti+a)<<12) + ((size_t)(4*tj+c)<<6) + (size_t)(4*tk));
        if (v.x!=0.f || v.y!=0.f || v.z!=0.f || v.w!=0.f){ any = true; }
      }
  }
  tnz[t] = any ? 1 : 0;
}

// ================= uniform-flow span loader: clamped address + zero predication ====
// Loads execute unconditionally from a safe (clamped) address; OOB rows/elements are
// zeroed via selects. Values identical to the branchy version -> downstream math
// contributes fma(w, 0, acc) == acc for masked taps -> bit-identical results.
template<int XT, int STRIDE, typename TIN, typename ACC>
__device__ __forceinline__ void load_span_u(const TIN* __restrict__ inr, bool ok, bool xlo, bool xhi,
                                            ACC (&xv)[STRIDE*(XT-1)+3]){
  static_assert(XT==4, "XT must be 4");
  typedef typename V4T<TIN>::type tin4;
  if (STRIDE==1){
    tin4 m = *(const tin4*)(inr + 1);
    xv[1]=(ACC)(ok ? m.x : (TIN)0); xv[2]=(ACC)(ok ? m.y : (TIN)0);
    xv[3]=(ACC)(ok ? m.z : (TIN)0); xv[4]=(ACC)(ok ? m.w : (TIN)0);
    xv[0] = (ok && xlo) ? (ACC)inr[0] : (ACC)0;
    xv[5] = (ok && xhi) ? (ACC)inr[5] : (ACC)0;
  } else {
    tin4 a = *(const tin4*)(inr + 1);
    tin4 b = *(const tin4*)(inr + 5);
    xv[1]=(ACC)(ok ? a.x : (TIN)0); xv[2]=(ACC)(ok ? a.y : (TIN)0);
    xv[3]=(ACC)(ok ? a.z : (TIN)0); xv[4]=(ACC)(ok ? a.w : (TIN)0);
    xv[5]=(ACC)(ok ? b.x : (TIN)0); xv[6]=(ACC)(ok ? b.y : (TIN)0);
    xv[7]=(ACC)(ok ? b.z : (TIN)0); xv[8]=(ACC)(ok ? b.w : (TIN)0);
    xv[0] = (ok && xlo) ? (ACC)inr[0] : (ACC)0;
  }
}

// ================= x-microtiled oc-fused 3x3x3 conv (UNIFORM control flow) =========
// No divergent continue: weight addresses sit in uniform flow -> scalar s_load path.
template<int CIN, int OCB, int XT, int STRIDE, bool DOSILU, typename TIN, typename TOUT, typename ACC>
__global__ void r20_conv3x3(const TIN* __restrict__ in, const float* __restrict__ w,
                            const float* __restrict__ bias, TOUT* __restrict__ out,
                            int Din, int Dout){
  constexpr int SPAN = STRIDE*(XT-1)+3;
  const int oc0 = blockIdx.y * OCB;
  const int n3 = Dout*Dout*Dout;
  const int nxt = Dout / XT;
  const int t = blockIdx.x*256 + threadIdx.x;
  const int xo0 = (t % nxt)*XT;
  const int yo = (t/nxt)%Dout, zo = t/(nxt*Dout);
  const int zi0 = zo*STRIDE-1, yi0 = yo*STRIDE-1, xi0 = xo0*STRIDE-1;
  const bool xlo = (xi0 >= 0);
  const bool xhi = (xi0 + (SPAN-1) < Din);

  ACC acc[OCB][XT];
  #pragma unroll
  for (int q=0;q<OCB;++q){
    ACC bv = (ACC)bias[oc0+q];
    #pragma unroll
    for (int s=0;s<XT;++s) acc[q][s] = bv;
  }

  #pragma unroll 1
  for (int i=0;i<CIN;++i){
    const TIN* inc = in + (size_t)i*Din*Din*Din;
    const float* wci = w + ((size_t)oc0*CIN + i)*27;
    #pragma unroll
    for (int kd=0;kd<3;++kd){
      int z = zi0+kd;
      bool okz = (unsigned)z < (unsigned)Din;
      int ze = okz ? z : 0;
      #pragma unroll
      for (int kh=0;kh<3;++kh){
        int y = yi0+kh;
        bool oky = (unsigned)y < (unsigned)Din;
        bool ok = okz && oky;
        int ye = oky ? y : 0;
        const TIN* inr = inc + ((size_t)ze*Din + ye)*Din + xi0;
        ACC xv[SPAN];
        load_span_u<XT,STRIDE,TIN,ACC>(inr, ok, xlo, xhi, xv);
        #pragma unroll
        for (int q=0;q<OCB;++q){
          const float* wr = wci + (size_t)q*CIN*27 + kd*9 + kh*3;
          #pragma unroll
          for (int kw=0;kw<3;++kw){
            ACC wv = (ACC)wr[kw];
            #pragma unroll
            for (int s=0;s<XT;++s)
              acc[q][s] = fma(wv, xv[s*STRIDE+kw], acc[q][s]);
          }
        }
      }
    }
  }
  if (DOSILU){
    #pragma unroll
    for (int q=0;q<OCB;++q)
      #pragma unroll
      for (int s=0;s<XT;++s){
        if (sizeof(ACC)==8) acc[q][s] = (ACC)silu_d((double)acc[q][s]);
        else                acc[q][s] = (ACC)silu_f((float)acc[q][s]);
      }
  }
  size_t vox = ((size_t)zo*Dout + yo)*Dout + xo0;
  #pragma unroll
  for (int q=0;q<OCB;++q)
    #pragma unroll
    for (int s=0;s<XT;++s)
      out[(size_t)(oc0+q)*n3 + vox + s] = (TOUT)acc[q][s];
}

// ================= x-microtiled ci-split conv (partials; uniform flow) =============
template<int CIN, int OCB, int XT, int NS, int STRIDE, typename TIN, typename ACC>
__global__ void r20_conv_part(const TIN* __restrict__ in, const float* __restrict__ w,
                              const float* __restrict__ bias, ACC* __restrict__ part,
                              int Din, int Dout){
  constexpr int SPAN = STRIDE*(XT-1)+3;
  const int oc0 = blockIdx.y * OCB;
  const int OC  = gridDim.y * OCB;
  const int cz  = blockIdx.z;
  const int n3 = Dout*Dout*Dout;
  const int nxt = Dout / XT;
  const int t = blockIdx.x*256 + threadIdx.x;
  const int xo0 = (t % nxt)*XT;
  const int yo = (t/nxt)%Dout, zo = t/(nxt*Dout);
  const int zi0 = zo*STRIDE-1, yi0 = yo*STRIDE-1, xi0 = xo0*STRIDE-1;
  const bool xlo = (xi0 >= 0);
  const bool xhi = (xi0 + (SPAN-1) < Din);

  ACC acc[OCB][XT];
  #pragma unroll
  for (int q=0;q<OCB;++q){
    ACC bv = (cz==0) ? (ACC)bias[oc0+q] : (ACC)0;
    #pragma unroll
    for (int s=0;s<XT;++s) acc[q][s] = bv;
  }

  const int cbeg = cz * (CIN/NS);
  #pragma unroll 1
  for (int i=cbeg; i<cbeg + CIN/NS; ++i){
    const TIN* inc = in + (size_t)i*Din*Din*Din;
    const float* wci = w + ((size_t)oc0*CIN + i)*27;
    #pragma unroll
    for (int kd=0;kd<3;++kd){
      int z = zi0+kd;
      bool okz = (unsigned)z < (unsigned)Din;
      int ze = okz ? z : 0;
      #pragma unroll
      for (int kh=0;kh<3;++kh){
        int y = yi0+kh;
        bool oky = (unsigned)y < (unsigned)Din;
        bool ok = okz && oky;
        int ye = oky ? y : 0;
        const TIN* inr = inc + ((size_t)ze*Din + ye)*Din + xi0;
        ACC xv[SPAN];
        load_span_u<XT,STRIDE,TIN,ACC>(inr, ok, xlo, xhi, xv);
        #pragma unroll
        for (int q=0;q<OCB;++q){
          const float* wr = wci + (size_t)q*CIN*27 + kd*9 + kh*3;
          #pragma unroll
          for (int kw=0;kw<3;++kw){
            ACC wv = (ACC)wr[kw];
            #pragma unroll
            for (int s=0;s<XT;++s)
              acc[q][s] = fma(wv, xv[s*STRIDE+kw], acc[q][s]);
          }
        }
      }
    }
  }
  size_t vox = ((size_t)zo*Dout + yo)*Dout + xo0;
  #pragma unroll
  for (int q=0;q<OCB;++q)
    #pragma unroll
    for (int s=0;s<XT;++s)
      part[((size_t)cz*OC + (oc0+q))*n3 + vox + s] = acc[q][s];
}

// ================= batched ci-split conv (uniform flow): grid.z = batch*NS + slice ==
template<int CIN, int OCB, int XT, int NS, int STRIDE, typename TIN, typename ACC>
__global__ void r20_conv_part_b(const TIN* __restrict__ in_all, size_t in_bstride,
                                const float* __restrict__ w, const float* __restrict__ bias,
                                ACC* __restrict__ part, int Din, int Dout){
  constexpr int SPAN = STRIDE*(XT-1)+3;
  const int oc0 = blockIdx.y * OCB;
  const int OC  = gridDim.y * OCB;
  const int bz  = blockIdx.z / NS;
  const int cz  = blockIdx.z % NS;
  const TIN* in = in_all + (size_t)bz*in_bstride;
  const int n3 = Dout*Dout*Dout;
  const int nxt = Dout / XT;
  const int t = blockIdx.x*256 + threadIdx.x;
  const int xo0 = (t % nxt)*XT;
  const int yo = (t/nxt)%Dout, zo = t/(nxt*Dout);
  const int zi0 = zo*STRIDE-1, yi0 = yo*STRIDE-1, xi0 = xo0*STRIDE-1;
  const bool xlo = (xi0 >= 0);
  const bool xhi = (xi0 + (SPAN-1) < Din);

  ACC acc[OCB][XT];
  #pragma unroll
  for (int q=0;q<OCB;++q){
    ACC bv = (cz==0) ? (ACC)bias[oc0+q] : (ACC)0;
    #pragma unroll
    for (int s=0;s<XT;++s) acc[q][s] = bv;
  }

  const int cbeg = cz * (CIN/NS);
  #pragma unroll 1
  for (int i=cbeg; i<cbeg + CIN/NS; ++i){
    const TIN* inc = in + (size_t)i*Din*Din*Din;
    const float* wci = w + ((size_t)oc0*CIN + i)*27;
    #pragma unroll
    for (int kd=0;kd<3;++kd){
      int z = zi0+kd;
      bool okz = (unsigned)z < (unsigned)Din;
      int ze = okz ? z : 0;
      #pragma unroll
      for (int kh=0;kh<3;++kh){
        int y = yi0+kh;
        bool oky = (unsigned)y < (unsigned)Din;
        bool ok = okz && oky;
        int ye = oky ? y : 0;
        const TIN* inr = inc + ((size_t)ze*Din + ye)*Din + xi0;
        ACC xv[SPAN];
        load_span_u<XT,STRIDE,TIN,ACC>(inr, ok, xlo, xhi, xv);
        #pragma unroll
        for (int q=0;q<OCB;++q){
          const float* wr = wci + (size_t)q*CIN*27 + kd*9 + kh*3;
          #pragma unroll
          for (int kw=0;kw<3;++kw){
            ACC wv = (ACC)wr[kw];
            #pragma unroll
            for (int s=0;s<XT;++s)
              acc[q][s] = fma(wv, xv[s*STRIDE+kw], acc[q][s]);
          }
        }
      }
    }
  }
  size_t vox = ((size_t)zo*Dout + yo)*Dout + xo0;
  #pragma unroll
  for (int q=0;q<OCB;++q)
    #pragma unroll
    for (int s=0;s<XT;++s)
      part[((size_t)(bz*NS+cz)*OC + (oc0+q))*n3 + vox + s] = acc[q][s];
}

// ================= vectorized deterministic reduces =================
template<int NS, int VEC, bool DOSILU, typename ACC, typename TOUT>
__global__ void r16_reduce(const ACC* __restrict__ part, TOUT* __restrict__ out, int total){
  int t0 = (blockIdx.x*256 + threadIdx.x)*VEC;
  if (t0 >= total) return;
  ACC a[VEC];
  #pragma unroll
  for (int v=0;v<VEC;++v) a[v] = part[t0+v];
  #pragma unroll
  for (int s=1;s<NS;++s){
    #pragma unroll
    for (int v=0;v<VEC;++v) a[v] += part[(size_t)s*total + t0+v];
  }
  #pragma unroll
  for (int v=0;v<VEC;++v){
    if (DOSILU){
      if (sizeof(ACC)==8) a[v] = (ACC)silu_d((double)a[v]);
      else                a[v] = (ACC)silu_f((float)a[v]);
    }
    out[t0+v] = (TOUT)a[v];
  }
}

template<int NS, int VEC, bool DOSILU, typename ACC, typename TOUT>
__global__ void r18_reduce_b(const ACC* __restrict__ part, TOUT* __restrict__ out, int total){
  int b = blockIdx.y;
  int t0 = (blockIdx.x*256 + threadIdx.x)*VEC;
  if (t0 >= total) return;
  const ACC* pb = part + (size_t)b*NS*total;
  ACC a[VEC];
  #pragma unroll
  for (int v=0;v<VEC;++v) a[v] = pb[t0+v];
  #pragma unroll
  for (int s=1;s<NS;++s){
    #pragma unroll
    for (int v=0;v<VEC;++v) a[v] += pb[(size_t)s*total + t0+v];
  }
  #pragma unroll
  for (int v=0;v<VEC;++v){
    if (DOSILU){
      if (sizeof(ACC)==8) a[v] = (ACC)silu_d((double)a[v]);
      else                a[v] = (ACC)silu_f((float)a[v]);
    }
    out[(size_t)b*total + t0+v] = (TOUT)a[v];
  }
}

// ================= quantconv absorbing NS=4 reduce (pair of batches) =================
__global__ void r19_quantconv4(const double* __restrict__ parts, const float* __restrict__ w,
                               const float* __restrict__ bias, double* __restrict__ seqd, int bbase){
  int t = blockIdx.x*256 + threadIdx.x;    // 2*16*4096 = 131072
  int n = t & 4095, e = (t>>12)&15, bp = t>>16;
  const double* p0 = parts + (size_t)(bp*4+0)*524288 + n;
  const double* p1 = parts + (size_t)(bp*4+1)*524288 + n;
  const double* p2 = parts + (size_t)(bp*4+2)*524288 + n;
  const double* p3 = parts + (size_t)(bp*4+3)*524288 + n;
  double acc = (double)bias[e];
  const float* we = w + e*128;
  for (int i=0;i<128;++i){
    size_t o = (size_t)i<<12;
    double val = ((p0[o]+p1[o])+p2[o])+p3[o];
    acc = fma(val, (double)we[i], acc);
  }
  seqd[((size_t)((bbase+bp)*NTOK+n))*ED + e] = acc;
}

// ================= batched postquant (all 4 batches) =================
__global__ void r19_postquant_all(const float* __restrict__ qpe, const float* __restrict__ w,
                                  const float* __restrict__ bias, float* __restrict__ pq_all){
  int t = blockIdx.x*256 + threadIdx.x;    // 4*128*4096 = 2097152
  int n = t & 4095, o = (t>>12)&127, b = t>>19;
  const float* qpeb = qpe + (size_t)b*65536;
  float acc = bias[o];
  const float* wo = w + o*16;
  #pragma unroll
  for (int e=0;e<16;++e) acc = fmaf(qpeb[((size_t)e<<12)+n], wo[e], acc);
  pq_all[t] = acc;
}

// ================= VQ (float64) =================
__global__ void r9_cnorm(const float* __restrict__ cb, double* __restrict__ cnormd){
  int k = blockIdx.x*256 + threadIdx.x;
  if (k >= KCB) return;
  const float* c = cb + (size_t)k*ED;
  double s = 0.0;
  #pragma unroll
  for (int e=0;e<ED;++e) s = fma((double)c[e], (double)c[e], s);
  cnormd[k] = s;
}

#define VQC 256
#define VQPARTS 32
template<int PARTS>
__global__ void r18_vq_partial(const double* __restrict__ seqd, const float* __restrict__ cb,
                               const double* __restrict__ cnormd,
                               double* __restrict__ pdist, int* __restrict__ pidx){
  __shared__ double scb[VQC*ED];
  __shared__ double snorm[VQC];
  const int part = blockIdx.y;
  const int tok0 = blockIdx.x*256 + threadIdx.x;   // 32 blocks -> 0..8191
  const int tok1 = tok0 + 8192;
  double s0[16], s1[16];
  const double* sr0 = seqd + (size_t)tok0*ED;
  const double* sr1 = seqd + (size_t)tok1*ED;
  #pragma unroll
  for (int e=0;e<16;++e){ s0[e] = sr0[e]; s1[e] = sr1[e]; }
  const int kbase = part * (KCB/PARTS);
  for (int u=threadIdx.x; u<VQC*ED; u+=256) scb[u] = (double)cb[(size_t)kbase*ED + u];
  for (int u=threadIdx.x; u<VQC; u+=256) snorm[u] = cnormd[kbase+u];
  __syncthreads();
  double best0 = 1.0e300, best1 = 1.0e300; int bi0 = 0, bi1 = 0;
  for (int kk=0; kk<VQC; ++kk){
    const double* cr = scb + kk*ED;
    double dot0 = 0.0, dot1 = 0.0;
    #pragma unroll
    for (int e=0;e<16;++e){
      double c = cr[e];
      dot0 = fma(s0[e], c, dot0);
      dot1 = fma(s1[e], c, dot1);
    }
    double nm = snorm[kk];
    double d0 = nm - 2.0*dot0;
    double d1 = nm - 2.0*dot1;
    if (d0 < best0){ best0 = d0; bi0 = kbase+kk; }
    if (d1 < best1){ best1 = d1; bi1 = kbase+kk; }
  }
  pdist[part*16384 + tok0] = best0;
  pidx [part*16384 + tok0] = bi0;
  pdist[part*16384 + tok1] = best1;
  pidx [part*16384 + tok1] = bi1;
}

template<int PARTS>
__global__ void r12_vq_merge(const double* __restrict__ pdist, const int* __restrict__ pidx,
                             const unsigned char* __restrict__ tnz, int* __restrict__ idxw,
                             float* __restrict__ out_idx, float* __restrict__ loss_slot){
  int tok = blockIdx.x*256 + threadIdx.x;
  if (tok == 0) *loss_slot = 0.f;
  double best = pdist[tok]; int bi = pidx[tok];
  #pragma unroll
  for (int p=1;p<PARTS;++p){
    double d2 = pdist[p*16384+tok];
    if (d2 < best){ best = d2; bi = pidx[p*16384+tok]; }
  }
  idxw[tok] = bi;
  out_idx[tok] = tnz[tok] ? (float)(bi+1) : 0.f;
}

__global__ void r9_commit(const double* __restrict__ seqd, const float* __restrict__ cb,
                          const int* __restrict__ idxw, const unsigned char* __restrict__ tnz,
                          float* __restrict__ loss_slot){
  int tok = blockIdx.x*256 + threadIdx.x;
  float v = 0.f;
  if (tnz[tok]){
    const float* c = cb + (size_t)idxw[tok]*ED;
    const double* s = seqd + (size_t)tok*ED;
    double acc = 0.0;
    #pragma unroll
    for (int e=0;e<ED;++e){ double d = (double)c[e]-s[e]; acc = fma(d,d,acc); }
    v = (float)(acc * (0.25/(16.0*16384.0)));
  }
  #pragma unroll
  for (int off=32; off; off>>=1) v += __shfl_down(v, off);
  if ((threadIdx.x & 63) == 0) atomicAdd(loss_slot, v);
}

__global__ void r9_gather_pos(const float* __restrict__ cb, const float* __restrict__ rep,
                              const int* __restrict__ idxw, const unsigned char* __restrict__ tnz,
                              const float* __restrict__ pos, float* __restrict__ qpe){
  int t = blockIdx.x*256 + threadIdx.x;   // B*16*4096
  int n = t & 4095, e = (t>>12)&15, b = t>>16;
  int tok = b*NTOK + n;
  float v = tnz[tok] ? cb[(size_t)idxw[tok]*ED + e] : rep[e];
  qpe[t] = v + pos[((size_t)e<<12) + n];
}

// ================= parity-fused + x-microtiled transposed conv =================
template<int CIN, int XT, bool DOSILU>
__global__ void r16_tconv(const float* __restrict__ in, const float* __restrict__ w,
                          const float* __restrict__ bias, float* __restrict__ out,
                          int Din){
  static_assert(XT==2, "XT must be 2");
  const int oc = blockIdx.y;
  const int nxt = Din / XT;
  const int t = blockIdx.x*256 + threadIdx.x;
  const int ux0 = (t % nxt)*XT;
  const int uy = (t/nxt)%Din, uz = t/(nxt*Din);
  const bool vx = ux0 > 0, vy = uy > 0, vz = uz > 0;
  const int DD = Din*Din, n3 = DD*Din;

  float b0 = bias[oc];
  float acc[8][XT];
  #pragma unroll
  for (int q=0;q<8;++q)
    #pragma unroll
    for (int s=0;s<XT;++s) acc[q][s] = b0;

  const float* p = in + ((size_t)uz*Din + uy)*Din + ux0;
  #pragma unroll 1
  for (int i=0;i<CIN;++i){
    float X[2][2][XT+1];
    #pragma unroll
    for (int za=0; za<2; ++za){
      #pragma unroll
      for (int ya=0; ya<2; ++ya){
        bool okzy = (za==1 || vz) && (ya==1 || vy);
        const float* pr = p + (za-1)*DD + (ya-1)*Din;
        if (okzy){
          f2v m = *(const f2v*)(pr);
          X[za][ya][1] = m.x; X[za][ya][2] = m.y;
          X[za][ya][0] = vx ? pr[-1] : 0.f;
        } else {
          X[za][ya][0] = 0.f; X[za][ya][1] = 0.f; X[za][ya][2] = 0.f;
        }
      }
    }
    const float* wi = w + ((size_t)(oc*CIN) + i)*27;
    #pragma unroll
    for (int kd=0;kd<3;++kd){
      #pragma unroll
      for (int kh=0;kh<3;++kh){
        #pragma unroll
        for (int kw=0;kw<3;++kw){
          const int pz = (kd==1) ? 1 : 0, py = (kh==1) ? 1 : 0, px = (kw==1) ? 1 : 0;
          const int za = (kd==0) ? 0 : 1, ya = (kh==0) ? 0 : 1, xa = (kw==0) ? 0 : 1;
          float wv = wi[kd*9+kh*3+kw];
          #pragma unroll
          for (int s=0;s<XT;++s)
            acc[pz*4+py*2+px][s] = fmaf(wv, X[za][ya][s+xa], acc[pz*4+py*2+px][s]);
        }
      }
    }
    p += n3;
  }
  if (DOSILU){
    #pragma unroll
    for (int q=0;q<8;++q)
      #pragma unroll
      for (int s=0;s<XT;++s) acc[q][s] = silu_f(acc[q][s]);
  }
  const int Dout = 2*Din;
  #pragma unroll
  for (int pz=0; pz<2; ++pz){
    #pragma unroll
    for (int py=0; py<2; ++py){
      float* row = out + (((size_t)oc*Dout + 2*uz+pz)*Dout + (2*uy+py))*Dout + 2*ux0;
      #pragma unroll
      for (int s=0;s<XT;++s){
        float2 v2 = make_float2(acc[pz*4+py*2+0][s], acc[pz*4+py*2+1][s]);
        *(float2*)(row + 2*s) = v2;
      }
    }
  }
}

// ================= batched tconv (NS=1): grid.z = batch =================
template<int CIN, int XT, bool DOSILU>
__global__ void r19_tconv_b(const float* __restrict__ in_all, size_t in_bstride,
                            const float* __restrict__ w, const float* __restrict__ bias,
                            float* __restrict__ out_all, size_t out_bstride, int Din){
  static_assert(XT==2, "XT must be 2");
  const int oc = blockIdx.y;
  const int bz = blockIdx.z;
  const float* in = in_all + (size_t)bz*in_bstride;
  float* out = out_all + (size_t)bz*out_bstride;
  const int nxt = Din / XT;
  const int t = blockIdx.x*256 + threadIdx.x;
  const int ux0 = (t % nxt)*XT;
  const int uy = (t/nxt)%Din, uz = t/(nxt*Din);
  const bool vx = ux0 > 0, vy = uy > 0, vz = uz > 0;
  const int DD = Din*Din, n3 = DD*Din;

  float b0 = bias[oc];
  float acc[8][XT];
  #pragma unroll
  for (int q=0;q<8;++q)
    #pragma unroll
    for (int s=0;s<XT;++s) acc[q][s] = b0;

  const float* p = in + ((size_t)uz*Din + uy)*Din + ux0;
  #pragma unroll 1
  for (int i=0;i<CIN;++i){
    float X[2][2][XT+1];
    #pragma unroll
    for (int za=0; za<2; ++za){
      #pragma unroll
      for (int ya=0; ya<2; ++ya){
        bool okzy = (za==1 || vz) && (ya==1 || vy);
        const float* pr = p + (za-1)*DD + (ya-1)*Din;
        if (okzy){
          f2v m = *(const f2v*)(pr);
          X[za][ya][1] = m.x; X[za][ya][2] = m.y;
          X[za][ya][0] = vx ? pr[-1] : 0.f;
        } else {
          X[za][ya][0] = 0.f; X[za][ya][1] = 0.f; X[za][ya][2] = 0.f;
        }
      }
    }
    const float* wi = w + ((size_t)(oc*CIN) + i)*27;
    #pragma unroll
    for (int kd=0;kd<3;++kd){
      #pragma unroll
      for (int kh=0;kh<3;++kh){
        #pragma unroll
        for (int kw=0;kw<3;++kw){
          const int pz = (kd==1) ? 1 : 0, py = (kh==1) ? 1 : 0, px = (kw==1) ? 1 : 0;
          const int za = (kd==0) ? 0 : 1, ya = (kh==0) ? 0 : 1, xa = (kw==0) ? 0 : 1;
          float wv = wi[kd*9+kh*3+kw];
          #pragma unroll
          for (int s=0;s<XT;++s)
            acc[pz*4+py*2+px][s] = fmaf(wv, X[za][ya][s+xa], acc[pz*4+py*2+px][s]);
        }
      }
    }
    p += n3;
  }
  if (DOSILU){
    #pragma unroll
    for (int q=0;q<8;++q)
      #pragma unroll
      for (int s=0;s<XT;++s) acc[q][s] = silu_f(acc[q][s]);
  }
  const int Dout = 2*Din;
  #pragma unroll
  for (int pz=0; pz<2; ++pz){
    #pragma unroll
    for (int py=0; py<2; ++py){
      float* row = out + (((size_t)oc*Dout + 2*uz+pz)*Dout + (2*uy+py))*Dout + 2*ux0;
      #pragma unroll
      for (int s=0;s<XT;++s){
        float2 v2 = make_float2(acc[pz*4+py*2+0][s], acc[pz*4+py*2+1][s]);
        *(float2*)(row + 2*s) = v2;
      }
    }
  }
}

// diagnostic if workspace too small: out[0] = 9e6 + ws_MiB
__global__ void r9_diag_ws(float* out0, float v){
  if (threadIdx.x == 0 && blockIdx.x == 0) out0[0] = v;
}

// ================= launch =================
extern "C" void kernel_launch(void* const* d_in, const int* in_sizes, int n_in,
                              void* d_out, int out_size, void* d_ws, size_t ws_size,
                              hipStream_t stream){
  const unsigned char* x = (const unsigned char*)d_in[0];
  const float* enc_in_w  = (const float*)d_in[1];
  const float* enc_in_b  = (const float*)d_in[2];
  const float* enc_d1_w  = (const float*)d_in[3];
  const float* enc_d1_b  = (const float*)d_in[4];
  const float* enc_d2_w  = (const float*)d_in[5];
  const float* enc_d2_b  = (const float*)d_in[6];
  const float* enc_out_w = (const float*)d_in[7];
  const float* enc_out_b = (const float*)d_in[8];
  const float* quant_w   = (const float*)d_in[9];
  const float* quant_b   = (const float*)d_in[10];
  const float* codebook  = (const float*)d_in[11];
  const float* rep_tok   = (const float*)d_in[12];
  const float* pos_emb   = (const float*)d_in[13];
  const float* pq_w      = (const float*)d_in[14];
  const float* pq_b      = (const float*)d_in[15];
  const float* dec_in_w  = (const float*)d_in[16];
  const float* dec_in_b  = (const float*)d_in[17];
  const float* dec_u1_w  = (const float*)d_in[18];
  const float* dec_u1_b  = (const float*)d_in[19];
  const float* dec_u2_w  = (const float*)d_in[20];
  const float* dec_u2_b  = (const float*)d_in[21];
  const float* dec_out_w = (const float*)d_in[22];
  const float* dec_out_b = (const float*)d_in[23];

  float* out = (float*)d_out;
  const size_t OFF_RECON = 0;
  const size_t OFF_MC    = 8388608;
  const size_t OFF_LOSS  = 16777216;
  const size_t OFF_IDX   = 16777217;

  // ---- workspace layout (bytes); total 55.9 MiB, unchanged ----
  char* wsb = (char*)d_ws;
  float*  Sbig  = (float*) (wsb + 0);          // 33,554,432 : h1_b / u2_out / partials / VQ scratch
  double* seqd  = (double*)(wsb + 54525952);   //  2,097,152
  double* cnormd= (double*)(wsb + 56623104);   //     65,536
  int*    idxw  = (int*)   (wsb + 57475072);   //     65,536
  unsigned char* tnz = (unsigned char*)(wsb + 57540608); // 16,384
  float*  qpe   = (float*) (wsb + 57556992);   //  1,048,576
  int*    dflag = (int*)   (wsb + 58605568);   //         64
  const size_t WS_NEEDED = 58605632;

  // scratch aliases (all in ws; dead-window reuse):
  double* scr_d  = (double*)wsb;                    // f64 partials (Sbig), 32 MiB
  float*  scr_f  = (float*)wsb;                     // f32 partials (Sbig), 32 MiB
  float*  h2w    = (float*)(wsb + 33554432);        // h2 pair (2 x 8 MiB)
  double* h3w    = (double*)(wsb + 33554432);       // h3 pair (2 x 4 MiB f64)
  float*  pq_all = (float*)(wsb + 33554432);        // [4][128][4096] f32, 8 MiB
  float*  dD_all = (float*)(wsb + 41943040);        // [4][128][4096] f32, 8 MiB
  float*  scr_f2 = (float*)(wsb + 33554432);        // dec_out partials, 16 MiB
  double* pdist  = (double*)wsb;                    // VQ partial dists (Sbig)
  int*    pidx   = (int*)(wsb + VQPARTS*16384*8);   // VQ partial idx
  float*  u1_all = out + OFF_RECON;                 // [4][64][32768] f32 = 32 MiB (recon region; write-then-consume)

  dim3 blk(256);

  if (ws_size < WS_NEEDED){
    r9_diag_ws<<<dim3(1), dim3(64), 0, stream>>>(out + OFF_RECON,
        9.0e6f + (float)(ws_size >> 20));
    return;
  }

  // 0) input dtype probe (block-reduced flags)
  r9_probe_zero<<<dim3(1), dim3(64), 0, stream>>>(dflag);
  r17_probe<<<dim3(256), blk, 0, stream>>>(x, dflag);

  // 1) pack + token-nonzero mask
  r9_pack_mc<<<dim3(4096), blk, 0, stream>>>(x, out + OFF_MC, dflag);
  r9_token_nz<<<dim3(256), dim3(64), 0, stream>>>(out + OFF_MC, tnz);

  // 2) encoder, pair-wise (uniform-flow convs)
  for (int p = 0; p < 2; ++p){
    for (int bp = 0; bp < 2; ++bp){
      int b = 2*p + bp;
      const float* mcb = out + OFF_MC + (size_t)b*8*262144;
      r20_conv3x3<8,8,4,1,true,float,float,double>  <<<dim3(256,4,1), blk, 0, stream>>>(mcb,  enc_in_w, enc_in_b, Sbig, 64, 64);
      r20_conv3x3<32,4,4,2,true,float,float,double> <<<dim3(32,16,1), blk, 0, stream>>>(Sbig, enc_d1_w, enc_d1_b, h2w + (size_t)bp*2097152, 64, 32);
    }
    // enc_d2 pair: NS=4, grid (4,32,8) = 1024 blocks; partials 32 MiB f64 in Sbig
    r20_conv_part_b<64,4,4,4,2,float,double><<<dim3(4,32,8), blk, 0, stream>>>(h2w, 2097152, enc_d2_w, enc_d2_b, scr_d, 32, 16);
    r18_reduce_b<4,2,true,double,double><<<dim3(1024,2), blk, 0, stream>>>(scr_d, h3w, 524288);
    // enc_out pair: NS=4, grid (4,32,8) = 1024 blocks; partials back in Sbig
    r20_conv_part_b<128,4,4,4,1,double,double><<<dim3(4,32,8), blk, 0, stream>>>(h3w, 524288, enc_out_w, enc_out_b, scr_d, 16, 16);
    // quantconv absorbs the NS=4 reduce
    r19_quantconv4<<<dim3(512), blk, 0, stream>>>(scr_d, quant_w, quant_b, seqd, 2*p);
  }

  // 3) VQ (fp64): 32 partitions, 2-token-tiled -> grid (32,32) = 1024 blocks.
  r9_cnorm<<<dim3(32), blk, 0, stream>>>(codebook, cnormd);
  r18_vq_partial<VQPARTS><<<dim3(32,VQPARTS), blk, 0, stream>>>(seqd, codebook, cnormd, pdist, pidx);
  r12_vq_merge<VQPARTS><<<dim3(64), blk, 0, stream>>>(pdist, pidx, tnz, idxw, out + OFF_IDX, out + OFF_LOSS);
  r9_commit<<<dim3(64), blk, 0, stream>>>(seqd, codebook, idxw, tnz, out + OFF_LOSS);

  // 4) decoder: batched front half, per-batch back half
  r9_gather_pos<<<dim3(1024), blk, 0, stream>>>(codebook, rep_tok, idxw, tnz, pos_emb, qpe);
  r19_postquant_all<<<dim3(8192), blk, 0, stream>>>(qpe, pq_w, pq_b, pq_all);
  // dec_in batched: NS=4 -> grid (4,32,16) = 2048 blocks; partials 32 MiB f32 in Sbig
  r20_conv_part_b<128,4,4,4,1,float,float><<<dim3(4,32,16), blk, 0, stream>>>(pq_all, 524288, dec_in_w, dec_in_b, scr_f, 16, 16);
  r18_reduce_b<4,4,true,float,float><<<dim3(512,4), blk, 0, stream>>>(scr_f, dD_all, 524288);
  // dec_u1 batched NS=1: grid (8,64,4) = 2048 blocks; silu inline; out -> u1_all (write-only)
  r19_tconv_b<128,2,true><<<dim3(8,64,4), blk, 0, stream>>>(dD_all, 524288, dec_u1_w, dec_u1_b, u1_all, 2097152, 16);
  // per-batch back half
  for (int b = 0; b < BB; ++b){
    float* reconb = out + OFF_RECON + (size_t)b*2097152;
    r16_tconv<64,2,true> <<<dim3(64,32,1), blk, 0, stream>>>(u1_all + (size_t)b*2097152, dec_u2_w, dec_u2_b, Sbig, 32);
    r20_conv_part<32,8,4,2,1,float,float><<<dim3(256,1,2), blk, 0, stream>>>(Sbig, dec_out_w, dec_out_b, scr_f2, 64, 64);
    r16_reduce<2,4,false,float,float><<<dim3(2048), blk, 0, stream>>>(scr_f2, reconb, 2097152);
  }
}

// Round 14
// 3563.414 us; speedup vs baseline: 1.4975x; 1.4975x over previous
//
#include <hip/hip_runtime.h>
#include <hip/hip_bf16.h>
#include <math.h>

// ---- problem constants ----
#define BB 4
#define NTOK 4096
#define KCB 8192
#define ED 16

__device__ __forceinline__ float silu_f(float x){ return x / (1.0f + expf(-x)); }
__device__ __forceinline__ double silu_d(double x){ return x / (1.0 + exp(-x)); }

template<typename T> struct V4T { typedef T type __attribute__((ext_vector_type(4))); };
typedef float f2v __attribute__((ext_vector_type(2)));

// ================= input dtype probe: block-reduced flags =================
__global__ void r9_probe_zero(int* flags){ if (threadIdx.x < 2) flags[threadIdx.x] = 0; }

__global__ void r17_probe(const unsigned char* __restrict__ x, int* __restrict__ flags){
  __shared__ int so, sa;
  if (threadIdx.x == 0){ so = 0; sa = 0; }
  __syncthreads();
  const uint4* p = (const uint4*)x + (size_t)(blockIdx.x*256 + threadIdx.x)*4;
  unsigned uo = 0, ua = 0;
  #pragma unroll
  for (int r=0;r<4;++r){
    uint4 v = p[r];
    unsigned uw = v.x | v.y | v.z | v.w;
    uo |= (uw & 0xFFFFFF00u);
    ua |= (uw & 0x000000FFu);
  }
  if (uo) so = 1;
  if (ua) sa = 1;
  __syncthreads();
  if (threadIdx.x == 0){
    if (so) atomicOr(flags + 0, 1);
    if (sa) atomicOr(flags + 1, 1);
  }
}

// ================= pack bool -> multichannel (dtype-adaptive) =================
__global__ void r9_pack_mc(const unsigned char* __restrict__ x, float* __restrict__ mc,
                           const int* __restrict__ flags){
  int t = blockIdx.x*256 + threadIdx.x;          // B*64^3
  int k = t & 63, j = (t>>6)&63, i = (t>>12)&63, b = t>>18;
  int is_i32 = (flags[1] != 0) && (flags[0] == 0);
  unsigned ch[8];
  #pragma unroll
  for (int q=0;q<8;++q) ch[q]=0u;
  if (is_i32){
    const int* xb = (const int*)x + ((size_t)b << 24);
    #pragma unroll
    for (int a=0;a<4;++a){
      #pragma unroll
      for (int b2=0;b2<4;++b2){
        const int4 v = *(const int4*)(xb + (((size_t)(4*i+a))<<16) + ((size_t)(4*j+b2)<<8) + (size_t)(4*k));
        int vv[4] = {v.x, v.y, v.z, v.w};
        #pragma unroll
        for (int c2=0;c2<4;++c2){
          int lin = a*16 + b2*4 + c2;
          unsigned bit = vv[c2] ? 1u : 0u;
          ch[lin>>3] += bit << (lin&7);
        }
      }
    }
  } else {
    const unsigned char* xb = x + ((size_t)b << 24);
    #pragma unroll
    for (int a=0;a<4;++a){
      #pragma unroll
      for (int b2=0;b2<4;++b2){
        const unsigned char* row = xb + (((size_t)(4*i+a))<<16) + ((size_t)(4*j+b2)<<8) + (size_t)(4*k);
        unsigned v = *(const unsigned*)row;
        #pragma unroll
        for (int c2=0;c2<4;++c2){
          int lin = a*16 + b2*4 + c2;
          unsigned bit = ((v >> (8*c2)) & 0xffu) ? 1u : 0u;
          ch[lin>>3] += bit << (lin&7);
        }
      }
    }
  }
  size_t sp = ((size_t)i<<12) + (j<<6) + k;
  #pragma unroll
  for (int q=0;q<8;++q)
    mc[(((size_t)(b*8+q))<<18) + sp] = (float)ch[q] / 255.0f;
}

__global__ void r9_token_nz(const float* __restrict__ mc, unsigned char* __restrict__ tnz){
  int t = blockIdx.x*64 + threadIdx.x;   // 16384
  int tk = t&15, tj=(t>>4)&15, ti=(t>>8)&15, b=t>>12;
  bool any = false;
  for (int q=0;q<8 && !any;++q){
    const float* mq = mc + (((size_t)(b*8+q))<<18);
    for (int a=0;a<4;++a)
      for (int c=0;c<4;++c){
        const float4 v = *(const float4*)(mq + ((size_t)(4*ti+a)<<12) + ((size_t)(4*tj+c)<<6) + (size_t)(4*tk));
        if (v.x!=0.f || v.y!=0.f || v.z!=0.f || v.w!=0.f){ any = true; }
      }
  }
  tnz[t] = any ? 1 : 0;
}

// ================= span loader: vectorized interior + predicated edges =================
template<int XT, int STRIDE, typename TIN, typename ACC>
__device__ __forceinline__ void load_span(const TIN* __restrict__ inr, bool xlo, bool xhi,
                                          ACC (&xv)[STRIDE*(XT-1)+3]){
  static_assert(XT==4, "XT must be 4");
  typedef typename V4T<TIN>::type tin4;
  if (STRIDE==1){
    tin4 m = *(const tin4*)(inr + 1);
    xv[1]=(ACC)m.x; xv[2]=(ACC)m.y; xv[3]=(ACC)m.z; xv[4]=(ACC)m.w;
    xv[0] = xlo ? (ACC)inr[0] : (ACC)0;
    xv[5] = xhi ? (ACC)inr[5] : (ACC)0;
  } else {
    tin4 a = *(const tin4*)(inr + 1);
    tin4 b = *(const tin4*)(inr + 5);
    xv[1]=(ACC)a.x; xv[2]=(ACC)a.y; xv[3]=(ACC)a.z; xv[4]=(ACC)a.w;
    xv[5]=(ACC)b.x; xv[6]=(ACC)b.y; xv[7]=(ACC)b.z; xv[8]=(ACC)b.w;
    xv[0] = xlo ? (ACC)inr[0] : (ACC)0;
  }
}

// ================= x-microtiled oc-fused 3x3x3 conv (vectorized spans) =================
template<int CIN, int OCB, int XT, int STRIDE, bool DOSILU, typename TIN, typename TOUT, typename ACC>
__global__ void r16_conv3x3(const TIN* __restrict__ in, const float* __restrict__ w,
                            const float* __restrict__ bias, TOUT* __restrict__ out,
                            int Din, int Dout){
  constexpr int SPAN = STRIDE*(XT-1)+3;
  const int oc0 = blockIdx.y * OCB;
  const int n3 = Dout*Dout*Dout;
  const int nxt = Dout / XT;
  const int t = blockIdx.x*256 + threadIdx.x;
  const int xo0 = (t % nxt)*XT;
  const int yo = (t/nxt)%Dout, zo = t/(nxt*Dout);
  const int zi0 = zo*STRIDE-1, yi0 = yo*STRIDE-1, xi0 = xo0*STRIDE-1;
  const bool xlo = (xi0 >= 0);
  const bool xhi = (xi0 + (SPAN-1) < Din);

  ACC acc[OCB][XT];
  #pragma unroll
  for (int q=0;q<OCB;++q){
    ACC bv = (ACC)bias[oc0+q];
    #pragma unroll
    for (int s=0;s<XT;++s) acc[q][s] = bv;
  }

  #pragma unroll 1
  for (int i=0;i<CIN;++i){
    const TIN* inc = in + (size_t)i*Din*Din*Din;
    const float* wci = w + ((size_t)oc0*CIN + i)*27;
    #pragma unroll
    for (int kd=0;kd<3;++kd){
      int z = zi0+kd; if ((unsigned)z >= (unsigned)Din) continue;
      #pragma unroll
      for (int kh=0;kh<3;++kh){
        int y = yi0+kh; if ((unsigned)y >= (unsigned)Din) continue;
        const TIN* inr = inc + ((size_t)z*Din + y)*Din + xi0;
        ACC xv[SPAN];
        load_span<XT,STRIDE,TIN,ACC>(inr, xlo, xhi, xv);
        #pragma unroll
        for (int q=0;q<OCB;++q){
          const float* wr = wci + (size_t)q*CIN*27 + kd*9 + kh*3;
          #pragma unroll
          for (int kw=0;kw<3;++kw){
            ACC wv = (ACC)wr[kw];
            #pragma unroll
            for (int s=0;s<XT;++s)
              acc[q][s] = fma(wv, xv[s*STRIDE+kw], acc[q][s]);
          }
        }
      }
    }
  }
  if (DOSILU){
    #pragma unroll
    for (int q=0;q<OCB;++q)
      #pragma unroll
      for (int s=0;s<XT;++s){
        if (sizeof(ACC)==8) acc[q][s] = (ACC)silu_d((double)acc[q][s]);
        else                acc[q][s] = (ACC)silu_f((float)acc[q][s]);
      }
  }
  size_t vox = ((size_t)zo*Dout + yo)*Dout + xo0;
  #pragma unroll
  for (int q=0;q<OCB;++q)
    #pragma unroll
    for (int s=0;s<XT;++s)
      out[(size_t)(oc0+q)*n3 + vox + s] = (TOUT)acc[q][s];
}

// ================= x-microtiled ci-split conv (partials; single tensor) =================
template<int CIN, int OCB, int XT, int NS, int STRIDE, typename TIN, typename ACC>
__global__ void r16_conv_part(const TIN* __restrict__ in, const float* __restrict__ w,
                              const float* __restrict__ bias, ACC* __restrict__ part,
                              int Din, int Dout){
  constexpr int SPAN = STRIDE*(XT-1)+3;
  const int oc0 = blockIdx.y * OCB;
  const int OC  = gridDim.y * OCB;
  const int cz  = blockIdx.z;
  const int n3 = Dout*Dout*Dout;
  const int nxt = Dout / XT;
  const int t = blockIdx.x*256 + threadIdx.x;
  const int xo0 = (t % nxt)*XT;
  const int yo = (t/nxt)%Dout, zo = t/(nxt*Dout);
  const int zi0 = zo*STRIDE-1, yi0 = yo*STRIDE-1, xi0 = xo0*STRIDE-1;
  const bool xlo = (xi0 >= 0);
  const bool xhi = (xi0 + (SPAN-1) < Din);

  ACC acc[OCB][XT];
  #pragma unroll
  for (int q=0;q<OCB;++q){
    ACC bv = (cz==0) ? (ACC)bias[oc0+q] : (ACC)0;
    #pragma unroll
    for (int s=0;s<XT;++s) acc[q][s] = bv;
  }

  const int cbeg = cz * (CIN/NS);
  #pragma unroll 1
  for (int i=cbeg; i<cbeg + CIN/NS; ++i){
    const TIN* inc = in + (size_t)i*Din*Din*Din;
    const float* wci = w + ((size_t)oc0*CIN + i)*27;
    #pragma unroll
    for (int kd=0;kd<3;++kd){
      int z = zi0+kd; if ((unsigned)z >= (unsigned)Din) continue;
      #pragma unroll
      for (int kh=0;kh<3;++kh){
        int y = yi0+kh; if ((unsigned)y >= (unsigned)Din) continue;
        const TIN* inr = inc + ((size_t)z*Din + y)*Din + xi0;
        ACC xv[SPAN];
        load_span<XT,STRIDE,TIN,ACC>(inr, xlo, xhi, xv);
        #pragma unroll
        for (int q=0;q<OCB;++q){
          const float* wr = wci + (size_t)q*CIN*27 + kd*9 + kh*3;
          #pragma unroll
          for (int kw=0;kw<3;++kw){
            ACC wv = (ACC)wr[kw];
            #pragma unroll
            for (int s=0;s<XT;++s)
              acc[q][s] = fma(wv, xv[s*STRIDE+kw], acc[q][s]);
          }
        }
      }
    }
  }
  size_t vox = ((size_t)zo*Dout + yo)*Dout + xo0;
  #pragma unroll
  for (int q=0;q<OCB;++q)
    #pragma unroll
    for (int s=0;s<XT;++s)
      part[((size_t)cz*OC + (oc0+q))*n3 + vox + s] = acc[q][s];
}

// ================= batched ci-split conv, SLICE-MAJOR block order =================
// blockIdx.x = batch*NS + slice (fastest-varying -> XCD round-robin pins each XCD to
// ~one input slice, which fits its private 4 MiB L2); blockIdx.z = voxel chunk.
// Pure index permutation of the R12 kernel -> bit-identical results.
template<int CIN, int OCB, int XT, int NS, int STRIDE, typename TIN, typename ACC>
__global__ void r21_conv_part_b(const TIN* __restrict__ in_all, size_t in_bstride,
                                const float* __restrict__ w, const float* __restrict__ bias,
                                ACC* __restrict__ part, int Din, int Dout){
  constexpr int SPAN = STRIDE*(XT-1)+3;
  const int oc0 = blockIdx.y * OCB;
  const int OC  = gridDim.y * OCB;
  const int bz  = blockIdx.x / NS;
  const int cz  = blockIdx.x % NS;
  const TIN* in = in_all + (size_t)bz*in_bstride;
  const int n3 = Dout*Dout*Dout;
  const int nxt = Dout / XT;
  const int t = blockIdx.z*256 + threadIdx.x;
  const int xo0 = (t % nxt)*XT;
  const int yo = (t/nxt)%Dout, zo = t/(nxt*Dout);
  const int zi0 = zo*STRIDE-1, yi0 = yo*STRIDE-1, xi0 = xo0*STRIDE-1;
  const bool xlo = (xi0 >= 0);
  const bool xhi = (xi0 + (SPAN-1) < Din);

  ACC acc[OCB][XT];
  #pragma unroll
  for (int q=0;q<OCB;++q){
    ACC bv = (cz==0) ? (ACC)bias[oc0+q] : (ACC)0;
    #pragma unroll
    for (int s=0;s<XT;++s) acc[q][s] = bv;
  }

  const int cbeg = cz * (CIN/NS);
  #pragma unroll 1
  for (int i=cbeg; i<cbeg + CIN/NS; ++i){
    const TIN* inc = in + (size_t)i*Din*Din*Din;
    const float* wci = w + ((size_t)oc0*CIN + i)*27;
    #pragma unroll
    for (int kd=0;kd<3;++kd){
      int z = zi0+kd; if ((unsigned)z >= (unsigned)Din) continue;
      #pragma unroll
      for (int kh=0;kh<3;++kh){
        int y = yi0+kh; if ((unsigned)y >= (unsigned)Din) continue;
        const TIN* inr = inc + ((size_t)z*Din + y)*Din + xi0;
        ACC xv[SPAN];
        load_span<XT,STRIDE,TIN,ACC>(inr, xlo, xhi, xv);
        #pragma unroll
        for (int q=0;q<OCB;++q){
          const float* wr = wci + (size_t)q*CIN*27 + kd*9 + kh*3;
          #pragma unroll
          for (int kw=0;kw<3;++kw){
            ACC wv = (ACC)wr[kw];
            #pragma unroll
            for (int s=0;s<XT;++s)
              acc[q][s] = fma(wv, xv[s*STRIDE+kw], acc[q][s]);
          }
        }
      }
    }
  }
  size_t vox = ((size_t)zo*Dout + yo)*Dout + xo0;
  #pragma unroll
  for (int q=0;q<OCB;++q)
    #pragma unroll
    for (int s=0;s<XT;++s)
      part[((size_t)(bz*NS+cz)*OC + (oc0+q))*n3 + vox + s] = acc[q][s];
}

// ================= vectorized deterministic reduces =================
template<int NS, int VEC, bool DOSILU, typename ACC, typename TOUT>
__global__ void r16_reduce(const ACC* __restrict__ part, TOUT* __restrict__ out, int total){
  int t0 = (blockIdx.x*256 + threadIdx.x)*VEC;
  if (t0 >= total) return;
  ACC a[VEC];
  #pragma unroll
  for (int v=0;v<VEC;++v) a[v] = part[t0+v];
  #pragma unroll
  for (int s=1;s<NS;++s){
    #pragma unroll
    for (int v=0;v<VEC;++v) a[v] += part[(size_t)s*total + t0+v];
  }
  #pragma unroll
  for (int v=0;v<VEC;++v){
    if (DOSILU){
      if (sizeof(ACC)==8) a[v] = (ACC)silu_d((double)a[v]);
      else                a[v] = (ACC)silu_f((float)a[v]);
    }
    out[t0+v] = (TOUT)a[v];
  }
}

template<int NS, int VEC, bool DOSILU, typename ACC, typename TOUT>
__global__ void r18_reduce_b(const ACC* __restrict__ part, TOUT* __restrict__ out, int total){
  int b = blockIdx.y;
  int t0 = (blockIdx.x*256 + threadIdx.x)*VEC;
  if (t0 >= total) return;
  const ACC* pb = part + (size_t)b*NS*total;
  ACC a[VEC];
  #pragma unroll
  for (int v=0;v<VEC;++v) a[v] = pb[t0+v];
  #pragma unroll
  for (int s=1;s<NS;++s){
    #pragma unroll
    for (int v=0;v<VEC;++v) a[v] += pb[(size_t)s*total + t0+v];
  }
  #pragma unroll
  for (int v=0;v<VEC;++v){
    if (DOSILU){
      if (sizeof(ACC)==8) a[v] = (ACC)silu_d((double)a[v]);
      else                a[v] = (ACC)silu_f((float)a[v]);
    }
    out[(size_t)b*total + t0+v] = (TOUT)a[v];
  }
}

// ================= quantconv absorbing NS=4 reduce (pair of batches) =================
__global__ void r19_quantconv4(const double* __restrict__ parts, const float* __restrict__ w,
                               const float* __restrict__ bias, double* __restrict__ seqd, int bbase){
  int t = blockIdx.x*256 + threadIdx.x;    // 2*16*4096 = 131072
  int n = t & 4095, e = (t>>12)&15, bp = t>>16;
  const double* p0 = parts + (size_t)(bp*4+0)*524288 + n;
  const double* p1 = parts + (size_t)(bp*4+1)*524288 + n;
  const double* p2 = parts + (size_t)(bp*4+2)*524288 + n;
  const double* p3 = parts + (size_t)(bp*4+3)*524288 + n;
  double acc = (double)bias[e];
  const float* we = w + e*128;
  for (int i=0;i<128;++i){
    size_t o = (size_t)i<<12;
    double val = ((p0[o]+p1[o])+p2[o])+p3[o];
    acc = fma(val, (double)we[i], acc);
  }
  seqd[((size_t)((bbase+bp)*NTOK+n))*ED + e] = acc;
}

// ================= batched postquant (all 4 batches) =================
__global__ void r19_postquant_all(const float* __restrict__ qpe, const float* __restrict__ w,
                                  const float* __restrict__ bias, float* __restrict__ pq_all){
  int t = blockIdx.x*256 + threadIdx.x;    // 4*128*4096 = 2097152
  int n = t & 4095, o = (t>>12)&127, b = t>>19;
  const float* qpeb = qpe + (size_t)b*65536;
  float acc = bias[o];
  const float* wo = w + o*16;
  #pragma unroll
  for (int e=0;e<16;++e) acc = fmaf(qpeb[((size_t)e<<12)+n], wo[e], acc);
  pq_all[t] = acc;
}

// ================= VQ (float64) =================
__global__ void r9_cnorm(const float* __restrict__ cb, double* __restrict__ cnormd){
  int k = blockIdx.x*256 + threadIdx.x;
  if (k >= KCB) return;
  const float* c = cb + (size_t)k*ED;
  double s = 0.0;
  #pragma unroll
  for (int e=0;e<ED;++e) s = fma((double)c[e], (double)c[e], s);
  cnormd[k] = s;
}

#define VQC 256
#define VQPARTS 32
template<int PARTS>
__global__ void r18_vq_partial(const double* __restrict__ seqd, const float* __restrict__ cb,
                               const double* __restrict__ cnormd,
                               double* __restrict__ pdist, int* __restrict__ pidx){
  __shared__ double scb[VQC*ED];
  __shared__ double snorm[VQC];
  const int part = blockIdx.y;
  const int tok0 = blockIdx.x*256 + threadIdx.x;   // 32 blocks -> 0..8191
  const int tok1 = tok0 + 8192;
  double s0[16], s1[16];
  const double* sr0 = seqd + (size_t)tok0*ED;
  const double* sr1 = seqd + (size_t)tok1*ED;
  #pragma unroll
  for (int e=0;e<16;++e){ s0[e] = sr0[e]; s1[e] = sr1[e]; }
  const int kbase = part * (KCB/PARTS);
  for (int u=threadIdx.x; u<VQC*ED; u+=256) scb[u] = (double)cb[(size_t)kbase*ED + u];
  for (int u=threadIdx.x; u<VQC; u+=256) snorm[u] = cnormd[kbase+u];
  __syncthreads();
  double best0 = 1.0e300, best1 = 1.0e300; int bi0 = 0, bi1 = 0;
  for (int kk=0; kk<VQC; ++kk){
    const double* cr = scb + kk*ED;
    double dot0 = 0.0, dot1 = 0.0;
    #pragma unroll
    for (int e=0;e<16;++e){
      double c = cr[e];
      dot0 = fma(s0[e], c, dot0);
      dot1 = fma(s1[e], c, dot1);
    }
    double nm = snorm[kk];
    double d0 = nm - 2.0*dot0;
    double d1 = nm - 2.0*dot1;
    if (d0 < best0){ best0 = d0; bi0 = kbase+kk; }
    if (d1 < best1){ best1 = d1; bi1 = kbase+kk; }
  }
  pdist[part*16384 + tok0] = best0;
  pidx [part*16384 + tok0] = bi0;
  pdist[part*16384 + tok1] = best1;
  pidx [part*16384 + tok1] = bi1;
}

template<int PARTS>
__global__ void r12_vq_merge(const double* __restrict__ pdist, const int* __restrict__ pidx,
                             const unsigned char* __restrict__ tnz, int* __restrict__ idxw,
                             float* __restrict__ out_idx, float* __restrict__ loss_slot){
  int tok = blockIdx.x*256 + threadIdx.x;
  if (tok == 0) *loss_slot = 0.f;
  double best = pdist[tok]; int bi = pidx[tok];
  #pragma unroll
  for (int p=1;p<PARTS;++p){
    double d2 = pdist[p*16384+tok];
    if (d2 < best){ best = d2; bi = pidx[p*16384+tok]; }
  }
  idxw[tok] = bi;
  out_idx[tok] = tnz[tok] ? (float)(bi+1) : 0.f;
}

__global__ void r9_commit(const double* __restrict__ seqd, const float* __restrict__ cb,
                          const int* __restrict__ idxw, const unsigned char* __restrict__ tnz,
                          float* __restrict__ loss_slot){
  int tok = blockIdx.x*256 + threadIdx.x;
  float v = 0.f;
  if (tnz[tok]){
    const float* c = cb + (size_t)idxw[tok]*ED;
    const double* s = seqd + (size_t)tok*ED;
    double acc = 0.0;
    #pragma unroll
    for (int e=0;e<ED;++e){ double d = (double)c[e]-s[e]; acc = fma(d,d,acc); }
    v = (float)(acc * (0.25/(16.0*16384.0)));
  }
  #pragma unroll
  for (int off=32; off; off>>=1) v += __shfl_down(v, off);
  if ((threadIdx.x & 63) == 0) atomicAdd(loss_slot, v);
}

__global__ void r9_gather_pos(const float* __restrict__ cb, const float* __restrict__ rep,
                              const int* __restrict__ idxw, const unsigned char* __restrict__ tnz,
                              const float* __restrict__ pos, float* __restrict__ qpe){
  int t = blockIdx.x*256 + threadIdx.x;   // B*16*4096
  int n = t & 4095, e = (t>>12)&15, b = t>>16;
  int tok = b*NTOK + n;
  float v = tnz[tok] ? cb[(size_t)idxw[tok]*ED + e] : rep[e];
  qpe[t] = v + pos[((size_t)e<<12) + n];
}

// ================= parity-fused + x-microtiled transposed conv =================
template<int CIN, int XT, bool DOSILU>
__global__ void r16_tconv(const float* __restrict__ in, const float* __restrict__ w,
                          const float* __restrict__ bias, float* __restrict__ out,
                          int Din){
  static_assert(XT==2, "XT must be 2");
  const int oc = blockIdx.y;
  const int nxt = Din / XT;
  const int t = blockIdx.x*256 + threadIdx.x;
  const int ux0 = (t % nxt)*XT;
  const int uy = (t/nxt)%Din, uz = t/(nxt*Din);
  const bool vx = ux0 > 0, vy = uy > 0, vz = uz > 0;
  const int DD = Din*Din, n3 = DD*Din;

  float b0 = bias[oc];
  float acc[8][XT];
  #pragma unroll
  for (int q=0;q<8;++q)
    #pragma unroll
    for (int s=0;s<XT;++s) acc[q][s] = b0;

  const float* p = in + ((size_t)uz*Din + uy)*Din + ux0;
  #pragma unroll 1
  for (int i=0;i<CIN;++i){
    float X[2][2][XT+1];
    #pragma unroll
    for (int za=0; za<2; ++za){
      #pragma unroll
      for (int ya=0; ya<2; ++ya){
        bool okzy = (za==1 || vz) && (ya==1 || vy);
        const float* pr = p + (za-1)*DD + (ya-1)*Din;
        if (okzy){
          f2v m = *(const f2v*)(pr);
          X[za][ya][1] = m.x; X[za][ya][2] = m.y;
          X[za][ya][0] = vx ? pr[-1] : 0.f;
        } else {
          X[za][ya][0] = 0.f; X[za][ya][1] = 0.f; X[za][ya][2] = 0.f;
        }
      }
    }
    const float* wi = w + ((size_t)(oc*CIN) + i)*27;
    #pragma unroll
    for (int kd=0;kd<3;++kd){
      #pragma unroll
      for (int kh=0;kh<3;++kh){
        #pragma unroll
        for (int kw=0;kw<3;++kw){
          const int pz = (kd==1) ? 1 : 0, py = (kh==1) ? 1 : 0, px = (kw==1) ? 1 : 0;
          const int za = (kd==0) ? 0 : 1, ya = (kh==0) ? 0 : 1, xa = (kw==0) ? 0 : 1;
          float wv = wi[kd*9+kh*3+kw];
          #pragma unroll
          for (int s=0;s<XT;++s)
            acc[pz*4+py*2+px][s] = fmaf(wv, X[za][ya][s+xa], acc[pz*4+py*2+px][s]);
        }
      }
    }
    p += n3;
  }
  if (DOSILU){
    #pragma unroll
    for (int q=0;q<8;++q)
      #pragma unroll
      for (int s=0;s<XT;++s) acc[q][s] = silu_f(acc[q][s]);
  }
  const int Dout = 2*Din;
  #pragma unroll
  for (int pz=0; pz<2; ++pz){
    #pragma unroll
    for (int py=0; py<2; ++py){
      float* row = out + (((size_t)oc*Dout + 2*uz+pz)*Dout + (2*uy+py))*Dout + 2*ux0;
      #pragma unroll
      for (int s=0;s<XT;++s){
        float2 v2 = make_float2(acc[pz*4+py*2+0][s], acc[pz*4+py*2+1][s]);
        *(float2*)(row + 2*s) = v2;
      }
    }
  }
}

// ================= batched tconv (NS=1): grid.z = batch =================
template<int CIN, int XT, bool DOSILU>
__global__ void r19_tconv_b(const float* __restrict__ in_all, size_t in_bstride,
                            const float* __restrict__ w, const float* __restrict__ bias,
                            float* __restrict__ out_all, size_t out_bstride, int Din){
  static_assert(XT==2, "XT must be 2");
  const int oc = blockIdx.y;
  const int bz = blockIdx.z;
  const float* in = in_all + (size_t)bz*in_bstride;
  float* out = out_all + (size_t)bz*out_bstride;
  const int nxt = Din / XT;
  const int t = blockIdx.x*256 + threadIdx.x;
  const int ux0 = (t % nxt)*XT;
  const int uy = (t/nxt)%Din, uz = t/(nxt*Din);
  const bool vx = ux0 > 0, vy = uy > 0, vz = uz > 0;
  const int DD = Din*Din, n3 = DD*Din;

  float b0 = bias[oc];
  float acc[8][XT];
  #pragma unroll
  for (int q=0;q<8;++q)
    #pragma unroll
    for (int s=0;s<XT;++s) acc[q][s] = b0;

  const float* p = in + ((size_t)uz*Din + uy)*Din + ux0;
  #pragma unroll 1
  for (int i=0;i<CIN;++i){
    float X[2][2][XT+1];
    #pragma unroll
    for (int za=0; za<2; ++za){
      #pragma unroll
      for (int ya=0; ya<2; ++ya){
        bool okzy = (za==1 || vz) && (ya==1 || vy);
        const float* pr = p + (za-1)*DD + (ya-1)*Din;
        if (okzy){
          f2v m = *(const f2v*)(pr);
          X[za][ya][1] = m.x; X[za][ya][2] = m.y;
          X[za][ya][0] = vx ? pr[-1] : 0.f;
        } else {
          X[za][ya][0] = 0.f; X[za][ya][1] = 0.f; X[za][ya][2] = 0.f;
        }
      }
    }
    const float* wi = w + ((size_t)(oc*CIN) + i)*27;
    #pragma unroll
    for (int kd=0;kd<3;++kd){
      #pragma unroll
      for (int kh=0;kh<3;++kh){
        #pragma unroll
        for (int kw=0;kw<3;++kw){
          const int pz = (kd==1) ? 1 : 0, py = (kh==1) ? 1 : 0, px = (kw==1) ? 1 : 0;
          const int za = (kd==0) ? 0 : 1, ya = (kh==0) ? 0 : 1, xa = (kw==0) ? 0 : 1;
          float wv = wi[kd*9+kh*3+kw];
          #pragma unroll
          for (int s=0;s<XT;++s)
            acc[pz*4+py*2+px][s] = fmaf(wv, X[za][ya][s+xa], acc[pz*4+py*2+px][s]);
        }
      }
    }
    p += n3;
  }
  if (DOSILU){
    #pragma unroll
    for (int q=0;q<8;++q)
      #pragma unroll
      for (int s=0;s<XT;++s) acc[q][s] = silu_f(acc[q][s]);
  }
  const int Dout = 2*Din;
  #pragma unroll
  for (int pz=0; pz<2; ++pz){
    #pragma unroll
    for (int py=0; py<2; ++py){
      float* row = out + (((size_t)oc*Dout + 2*uz+pz)*Dout + (2*uy+py))*Dout + 2*ux0;
      #pragma unroll
      for (int s=0;s<XT;++s){
        float2 v2 = make_float2(acc[pz*4+py*2+0][s], acc[pz*4+py*2+1][s]);
        *(float2*)(row + 2*s) = v2;
      }
    }
  }
}

// diagnostic if workspace too small: out[0] = 9e6 + ws_MiB
__global__ void r9_diag_ws(float* out0, float v){
  if (threadIdx.x == 0 && blockIdx.x == 0) out0[0] = v;
}

// ================= launch =================
extern "C" void kernel_launch(void* const* d_in, const int* in_sizes, int n_in,
                              void* d_out, int out_size, void* d_ws, size_t ws_size,
                              hipStream_t stream){
  const unsigned char* x = (const unsigned char*)d_in[0];
  const float* enc_in_w  = (const float*)d_in[1];
  const float* enc_in_b  = (const float*)d_in[2];
  const float* enc_d1_w  = (const float*)d_in[3];
  const float* enc_d1_b  = (const float*)d_in[4];
  const float* enc_d2_w  = (const float*)d_in[5];
  const float* enc_d2_b  = (const float*)d_in[6];
  const float* enc_out_w = (const float*)d_in[7];
  const float* enc_out_b = (const float*)d_in[8];
  const float* quant_w   = (const float*)d_in[9];
  const float* quant_b   = (const float*)d_in[10];
  const float* codebook  = (const float*)d_in[11];
  const float* rep_tok   = (const float*)d_in[12];
  const float* pos_emb   = (const float*)d_in[13];
  const float* pq_w      = (const float*)d_in[14];
  const float* pq_b      = (const float*)d_in[15];
  const float* dec_in_w  = (const float*)d_in[16];
  const float* dec_in_b  = (const float*)d_in[17];
  const float* dec_u1_w  = (const float*)d_in[18];
  const float* dec_u1_b  = (const float*)d_in[19];
  const float* dec_u2_w  = (const float*)d_in[20];
  const float* dec_u2_b  = (const float*)d_in[21];
  const float* dec_out_w = (const float*)d_in[22];
  const float* dec_out_b = (const float*)d_in[23];

  float* out = (float*)d_out;
  const size_t OFF_RECON = 0;
  const size_t OFF_MC    = 8388608;
  const size_t OFF_LOSS  = 16777216;
  const size_t OFF_IDX   = 16777217;

  // ---- workspace layout (bytes); total 55.9 MiB, unchanged ----
  char* wsb = (char*)d_ws;
  float*  Sbig  = (float*) (wsb + 0);          // 33,554,432 : h1_b / u2_out / partials / VQ scratch
  double* seqd  = (double*)(wsb + 54525952);   //  2,097,152
  double* cnormd= (double*)(wsb + 56623104);   //     65,536
  int*    idxw  = (int*)   (wsb + 57475072);   //     65,536
  unsigned char* tnz = (unsigned char*)(wsb + 57540608); // 16,384
  float*  qpe   = (float*) (wsb + 57556992);   //  1,048,576
  int*    dflag = (int*)   (wsb + 58605568);   //         64
  const size_t WS_NEEDED = 58605632;

  // scratch aliases (all in ws; dead-window reuse):
  double* scr_d  = (double*)wsb;                    // f64 partials (Sbig), 32 MiB
  float*  scr_f  = (float*)wsb;                     // f32 partials (Sbig), 32 MiB
  float*  h2w    = (float*)(wsb + 33554432);        // h2 pair (2 x 8 MiB)
  double* h3w    = (double*)(wsb + 33554432);       // h3 pair (2 x 4 MiB f64)
  float*  pq_all = (float*)(wsb + 33554432);        // [4][128][4096] f32, 8 MiB
  float*  dD_all = (float*)(wsb + 41943040);        // [4][128][4096] f32, 8 MiB
  float*  scr_f2 = (float*)(wsb + 33554432);        // dec_out partials, 16 MiB
  double* pdist  = (double*)wsb;                    // VQ partial dists (Sbig)
  int*    pidx   = (int*)(wsb + VQPARTS*16384*8);   // VQ partial idx
  float*  u1_all = out + OFF_RECON;                 // [4][64][32768] f32 = 32 MiB (recon region; write-then-consume)

  dim3 blk(256);

  if (ws_size < WS_NEEDED){
    r9_diag_ws<<<dim3(1), dim3(64), 0, stream>>>(out + OFF_RECON,
        9.0e6f + (float)(ws_size >> 20));
    return;
  }

  // 0) input dtype probe (block-reduced flags)
  r9_probe_zero<<<dim3(1), dim3(64), 0, stream>>>(dflag);
  r17_probe<<<dim3(256), blk, 0, stream>>>(x, dflag);

  // 1) pack + token-nonzero mask
  r9_pack_mc<<<dim3(4096), blk, 0, stream>>>(x, out + OFF_MC, dflag);
  r9_token_nz<<<dim3(256), dim3(64), 0, stream>>>(out + OFF_MC, tnz);

  // 2) encoder, pair-wise (R12 kernels; slice-major batched parts)
  for (int p = 0; p < 2; ++p){
    for (int bp = 0; bp < 2; ++bp){
      int b = 2*p + bp;
      const float* mcb = out + OFF_MC + (size_t)b*8*262144;
      r16_conv3x3<8,8,4,1,true,float,float,double>  <<<dim3(256,4,1), blk, 0, stream>>>(mcb,  enc_in_w, enc_in_b, Sbig, 64, 64);
      r16_conv3x3<32,4,4,2,true,float,float,double> <<<dim3(32,16,1), blk, 0, stream>>>(Sbig, enc_d1_w, enc_d1_b, h2w + (size_t)bp*2097152, 64, 32);
    }
    // enc_d2 pair: NS=4, slice-major grid (8,32,4) = 1024 blocks; partials 32 MiB f64 in Sbig
    r21_conv_part_b<64,4,4,4,2,float,double><<<dim3(8,32,4), blk, 0, stream>>>(h2w, 2097152, enc_d2_w, enc_d2_b, scr_d, 32, 16);
    r18_reduce_b<4,2,true,double,double><<<dim3(1024,2), blk, 0, stream>>>(scr_d, h3w, 524288);
    // enc_out pair: NS=4, slice-major grid (8,32,4) = 1024 blocks; partials back in Sbig
    r21_conv_part_b<128,4,4,4,1,double,double><<<dim3(8,32,4), blk, 0, stream>>>(h3w, 524288, enc_out_w, enc_out_b, scr_d, 16, 16);
    // quantconv absorbs the NS=4 reduce
    r19_quantconv4<<<dim3(512), blk, 0, stream>>>(scr_d, quant_w, quant_b, seqd, 2*p);
  }

  // 3) VQ (fp64): 32 partitions, 2-token-tiled -> grid (32,32) = 1024 blocks.
  r9_cnorm<<<dim3(32), blk, 0, stream>>>(codebook, cnormd);
  r18_vq_partial<VQPARTS><<<dim3(32,VQPARTS), blk, 0, stream>>>(seqd, codebook, cnormd, pdist, pidx);
  r12_vq_merge<VQPARTS><<<dim3(64), blk, 0, stream>>>(pdist, pidx, tnz, idxw, out + OFF_IDX, out + OFF_LOSS);
  r9_commit<<<dim3(64), blk, 0, stream>>>(seqd, codebook, idxw, tnz, out + OFF_LOSS);

  // 4) decoder: batched front half, per-batch back half (R12 structure)
  r9_gather_pos<<<dim3(1024), blk, 0, stream>>>(codebook, rep_tok, idxw, tnz, pos_emb, qpe);
  r19_postquant_all<<<dim3(8192), blk, 0, stream>>>(qpe, pq_w, pq_b, pq_all);
  // dec_in batched: NS=4, slice-major grid (16,32,4) = 2048 blocks; partials 32 MiB f32 in Sbig
  r21_conv_part_b<128,4,4,4,1,float,float><<<dim3(16,32,4), blk, 0, stream>>>(pq_all, 524288, dec_in_w, dec_in_b, scr_f, 16, 16);
  r18_reduce_b<4,4,true,float,float><<<dim3(512,4), blk, 0, stream>>>(scr_f, dD_all, 524288);
  // dec_u1 batched NS=1: grid (8,64,4) = 2048 blocks; silu inline; out -> u1_all (write-only)
  r19_tconv_b<128,2,true><<<dim3(8,64,4), blk, 0, stream>>>(dD_all, 524288, dec_u1_w, dec_u1_b, u1_all, 2097152, 16);
  // per-batch back half
  for (int b = 0; b < BB; ++b){
    float* reconb = out + OFF_RECON + (size_t)b*2097152;
    r16_tconv<64,2,true> <<<dim3(64,32,1), blk, 0, stream>>>(u1_all + (size_t)b*2097152, dec_u2_w, dec_u2_b, Sbig, 32);
    r16_conv_part<32,8,4,2,1,float,float><<<dim3(256,1,2), blk, 0, stream>>>(Sbig, dec_out_w, dec_out_b, scr_f2, 64, 64);
    r16_reduce<2,4,false,float,float><<<dim3(2048), blk, 0, stream>>>(scr_f2, reconb, 2097152);
  }
}

// Round 15
// 3559.258 us; speedup vs baseline: 1.4993x; 1.0012x over previous
//
#include <hip/hip_runtime.h>
#include <hip/hip_bf16.h>
#include <math.h>

// ---- problem constants ----
#define BB 4
#define NTOK 4096
#define KCB 8192
#define ED 16

__device__ __forceinline__ float silu_f(float x){ return x / (1.0f + expf(-x)); }
__device__ __forceinline__ double silu_d(double x){ return x / (1.0 + exp(-x)); }

template<typename T> struct V4T { typedef T type __attribute__((ext_vector_type(4))); };
typedef float f2v __attribute__((ext_vector_type(2)));

// ================= input dtype probe: block-reduced flags =================
__global__ void r9_probe_zero(int* flags){ if (threadIdx.x < 2) flags[threadIdx.x] = 0; }

__global__ void r17_probe(const unsigned char* __restrict__ x, int* __restrict__ flags){
  __shared__ int so, sa;
  if (threadIdx.x == 0){ so = 0; sa = 0; }
  __syncthreads();
  const uint4* p = (const uint4*)x + (size_t)(blockIdx.x*256 + threadIdx.x)*4;
  unsigned uo = 0, ua = 0;
  #pragma unroll
  for (int r=0;r<4;++r){
    uint4 v = p[r];
    unsigned uw = v.x | v.y | v.z | v.w;
    uo |= (uw & 0xFFFFFF00u);
    ua |= (uw & 0x000000FFu);
  }
  if (uo) so = 1;
  if (ua) sa = 1;
  __syncthreads();
  if (threadIdx.x == 0){
    if (so) atomicOr(flags + 0, 1);
    if (sa) atomicOr(flags + 1, 1);
  }
}

// ================= pack bool -> multichannel (dtype-adaptive) =================
__global__ void r9_pack_mc(const unsigned char* __restrict__ x, float* __restrict__ mc,
                           const int* __restrict__ flags){
  int t = blockIdx.x*256 + threadIdx.x;          // B*64^3
  int k = t & 63, j = (t>>6)&63, i = (t>>12)&63, b = t>>18;
  int is_i32 = (flags[1] != 0) && (flags[0] == 0);
  unsigned ch[8];
  #pragma unroll
  for (int q=0;q<8;++q) ch[q]=0u;
  if (is_i32){
    const int* xb = (const int*)x + ((size_t)b << 24);
    #pragma unroll
    for (int a=0;a<4;++a){
      #pragma unroll
      for (int b2=0;b2<4;++b2){
        const int4 v = *(const int4*)(xb + (((size_t)(4*i+a))<<16) + ((size_t)(4*j+b2)<<8) + (size_t)(4*k));
        int vv[4] = {v.x, v.y, v.z, v.w};
        #pragma unroll
        for (int c2=0;c2<4;++c2){
          int lin = a*16 + b2*4 + c2;
          unsigned bit = vv[c2] ? 1u : 0u;
          ch[lin>>3] += bit << (lin&7);
        }
      }
    }
  } else {
    const unsigned char* xb = x + ((size_t)b << 24);
    #pragma unroll
    for (int a=0;a<4;++a){
      #pragma unroll
      for (int b2=0;b2<4;++b2){
        const unsigned char* row = xb + (((size_t)(4*i+a))<<16) + ((size_t)(4*j+b2)<<8) + (size_t)(4*k);
        unsigned v = *(const unsigned*)row;
        #pragma unroll
        for (int c2=0;c2<4;++c2){
          int lin = a*16 + b2*4 + c2;
          unsigned bit = ((v >> (8*c2)) & 0xffu) ? 1u : 0u;
          ch[lin>>3] += bit << (lin&7);
        }
      }
    }
  }
  size_t sp = ((size_t)i<<12) + (j<<6) + k;
  #pragma unroll
  for (int q=0;q<8;++q)
    mc[(((size_t)(b*8+q))<<18) + sp] = (float)ch[q] / 255.0f;
}

__global__ void r9_token_nz(const float* __restrict__ mc, unsigned char* __restrict__ tnz){
  int t = blockIdx.x*64 + threadIdx.x;   // 16384
  int tk = t&15, tj=(t>>4)&15, ti=(t>>8)&15, b=t>>12;
  bool any = false;
  for (int q=0;q<8 && !any;++q){
    const float* mq = mc + (((size_t)(b*8+q))<<18);
    for (int a=0;a<4;++a)
      for (int c=0;c<4;++c){
        const float4 v = *(const float4*)(mq + ((size_t)(4*ti+a)<<12) + ((size_t)(4*tj+c)<<6) + (size_t)(4*tk));
        if (v.x!=0.f || v.y!=0.f || v.z!=0.f || v.w!=0.f){ any = true; }
      }
  }
  tnz[t] = any ? 1 : 0;
}

// ================= span loader: vectorized interior + predicated edges =================
template<int XT, int STRIDE, typename TIN, typename ACC>
__device__ __forceinline__ void load_span(const TIN* __restrict__ inr, bool xlo, bool xhi,
                                          ACC (&xv)[STRIDE*(XT-1)+3]){
  static_assert(XT==4, "XT must be 4");
  typedef typename V4T<TIN>::type tin4;
  if (STRIDE==1){
    tin4 m = *(const tin4*)(inr + 1);
    xv[1]=(ACC)m.x; xv[2]=(ACC)m.y; xv[3]=(ACC)m.z; xv[4]=(ACC)m.w;
    xv[0] = xlo ? (ACC)inr[0] : (ACC)0;
    xv[5] = xhi ? (ACC)inr[5] : (ACC)0;
  } else {
    tin4 a = *(const tin4*)(inr + 1);
    tin4 b = *(const tin4*)(inr + 5);
    xv[1]=(ACC)a.x; xv[2]=(ACC)a.y; xv[3]=(ACC)a.z; xv[4]=(ACC)a.w;
    xv[5]=(ACC)b.x; xv[6]=(ACC)b.y; xv[7]=(ACC)b.z; xv[8]=(ACC)b.w;
    xv[0] = xlo ? (ACC)inr[0] : (ACC)0;
  }
}

// ================= weight-hoisted x-microtiled oc-fused 3x3x3 conv =================
// Weight loads hoisted ABOVE the divergent bounds check into uniform control flow
// (addresses depend only on blockIdx/loop vars) -> scalar s_load path; the divergent
// if() guards only span load + FMA. Skipped rows contribute nothing -> bit-identical.
template<int CIN, int OCB, int XT, int STRIDE, bool DOSILU, typename TIN, typename TOUT, typename ACC>
__global__ void r22_conv3x3(const TIN* __restrict__ in, const float* __restrict__ w,
                            const float* __restrict__ bias, TOUT* __restrict__ out,
                            int Din, int Dout){
  constexpr int SPAN = STRIDE*(XT-1)+3;
  const int oc0 = blockIdx.y * OCB;
  const int n3 = Dout*Dout*Dout;
  const int nxt = Dout / XT;
  const int t = blockIdx.x*256 + threadIdx.x;
  const int xo0 = (t % nxt)*XT;
  const int yo = (t/nxt)%Dout, zo = t/(nxt*Dout);
  const int zi0 = zo*STRIDE-1, yi0 = yo*STRIDE-1, xi0 = xo0*STRIDE-1;
  const bool xlo = (xi0 >= 0);
  const bool xhi = (xi0 + (SPAN-1) < Din);

  ACC acc[OCB][XT];
  #pragma unroll
  for (int q=0;q<OCB;++q){
    ACC bv = (ACC)bias[oc0+q];
    #pragma unroll
    for (int s=0;s<XT;++s) acc[q][s] = bv;
  }

  #pragma unroll 1
  for (int i=0;i<CIN;++i){
    const TIN* inc = in + (size_t)i*Din*Din*Din;
    const float* wci = w + ((size_t)oc0*CIN + i)*27;
    #pragma unroll
    for (int kd=0;kd<3;++kd){
      int z = zi0+kd;
      bool okz = (unsigned)z < (unsigned)Din;
      #pragma unroll
      for (int kh=0;kh<3;++kh){
        int y = yi0+kh;
        bool oky = (unsigned)y < (unsigned)Din;
        // uniform-flow weight fetch (scalar path)
        float wq[OCB][3];
        #pragma unroll
        for (int q=0;q<OCB;++q){
          const float* wr = wci + (size_t)q*CIN*27 + kd*9 + kh*3;
          #pragma unroll
          for (int kw=0;kw<3;++kw) wq[q][kw] = wr[kw];
        }
        if (okz && oky){
          const TIN* inr = inc + ((size_t)z*Din + y)*Din + xi0;
          ACC xv[SPAN];
          load_span<XT,STRIDE,TIN,ACC>(inr, xlo, xhi, xv);
          #pragma unroll
          for (int q=0;q<OCB;++q){
            #pragma unroll
            for (int kw=0;kw<3;++kw){
              ACC wv = (ACC)wq[q][kw];
              #pragma unroll
              for (int s=0;s<XT;++s)
                acc[q][s] = fma(wv, xv[s*STRIDE+kw], acc[q][s]);
            }
          }
        }
      }
    }
  }
  if (DOSILU){
    #pragma unroll
    for (int q=0;q<OCB;++q)
      #pragma unroll
      for (int s=0;s<XT;++s){
        if (sizeof(ACC)==8) acc[q][s] = (ACC)silu_d((double)acc[q][s]);
        else                acc[q][s] = (ACC)silu_f((float)acc[q][s]);
      }
  }
  size_t vox = ((size_t)zo*Dout + yo)*Dout + xo0;
  #pragma unroll
  for (int q=0;q<OCB;++q)
    #pragma unroll
    for (int s=0;s<XT;++s)
      out[(size_t)(oc0+q)*n3 + vox + s] = (TOUT)acc[q][s];
}

// ================= weight-hoisted ci-split conv (partials; single tensor) ===========
template<int CIN, int OCB, int XT, int NS, int STRIDE, typename TIN, typename ACC>
__global__ void r22_conv_part(const TIN* __restrict__ in, const float* __restrict__ w,
                              const float* __restrict__ bias, ACC* __restrict__ part,
                              int Din, int Dout){
  constexpr int SPAN = STRIDE*(XT-1)+3;
  const int oc0 = blockIdx.y * OCB;
  const int OC  = gridDim.y * OCB;
  const int cz  = blockIdx.z;
  const int n3 = Dout*Dout*Dout;
  const int nxt = Dout / XT;
  const int t = blockIdx.x*256 + threadIdx.x;
  const int xo0 = (t % nxt)*XT;
  const int yo = (t/nxt)%Dout, zo = t/(nxt*Dout);
  const int zi0 = zo*STRIDE-1, yi0 = yo*STRIDE-1, xi0 = xo0*STRIDE-1;
  const bool xlo = (xi0 >= 0);
  const bool xhi = (xi0 + (SPAN-1) < Din);

  ACC acc[OCB][XT];
  #pragma unroll
  for (int q=0;q<OCB;++q){
    ACC bv = (cz==0) ? (ACC)bias[oc0+q] : (ACC)0;
    #pragma unroll
    for (int s=0;s<XT;++s) acc[q][s] = bv;
  }

  const int cbeg = cz * (CIN/NS);
  #pragma unroll 1
  for (int i=cbeg; i<cbeg + CIN/NS; ++i){
    const TIN* inc = in + (size_t)i*Din*Din*Din;
    const float* wci = w + ((size_t)oc0*CIN + i)*27;
    #pragma unroll
    for (int kd=0;kd<3;++kd){
      int z = zi0+kd;
      bool okz = (unsigned)z < (unsigned)Din;
      #pragma unroll
      for (int kh=0;kh<3;++kh){
        int y = yi0+kh;
        bool oky = (unsigned)y < (unsigned)Din;
        float wq[OCB][3];
        #pragma unroll
        for (int q=0;q<OCB;++q){
          const float* wr = wci + (size_t)q*CIN*27 + kd*9 + kh*3;
          #pragma unroll
          for (int kw=0;kw<3;++kw) wq[q][kw] = wr[kw];
        }
        if (okz && oky){
          const TIN* inr = inc + ((size_t)z*Din + y)*Din + xi0;
          ACC xv[SPAN];
          load_span<XT,STRIDE,TIN,ACC>(inr, xlo, xhi, xv);
          #pragma unroll
          for (int q=0;q<OCB;++q){
            #pragma unroll
            for (int kw=0;kw<3;++kw){
              ACC wv = (ACC)wq[q][kw];
              #pragma unroll
              for (int s=0;s<XT;++s)
                acc[q][s] = fma(wv, xv[s*STRIDE+kw], acc[q][s]);
            }
          }
        }
      }
    }
  }
  size_t vox = ((size_t)zo*Dout + yo)*Dout + xo0;
  #pragma unroll
  for (int q=0;q<OCB;++q)
    #pragma unroll
    for (int s=0;s<XT;++s)
      part[((size_t)cz*OC + (oc0+q))*n3 + vox + s] = acc[q][s];
}

// ================= weight-hoisted batched ci-split conv, slice-major =================
template<int CIN, int OCB, int XT, int NS, int STRIDE, typename TIN, typename ACC>
__global__ void r22_conv_part_b(const TIN* __restrict__ in_all, size_t in_bstride,
                                const float* __restrict__ w, const float* __restrict__ bias,
                                ACC* __restrict__ part, int Din, int Dout){
  constexpr int SPAN = STRIDE*(XT-1)+3;
  const int oc0 = blockIdx.y * OCB;
  const int OC  = gridDim.y * OCB;
  const int bz  = blockIdx.x / NS;
  const int cz  = blockIdx.x % NS;
  const TIN* in = in_all + (size_t)bz*in_bstride;
  const int n3 = Dout*Dout*Dout;
  const int nxt = Dout / XT;
  const int t = blockIdx.z*256 + threadIdx.x;
  const int xo0 = (t % nxt)*XT;
  const int yo = (t/nxt)%Dout, zo = t/(nxt*Dout);
  const int zi0 = zo*STRIDE-1, yi0 = yo*STRIDE-1, xi0 = xo0*STRIDE-1;
  const bool xlo = (xi0 >= 0);
  const bool xhi = (xi0 + (SPAN-1) < Din);

  ACC acc[OCB][XT];
  #pragma unroll
  for (int q=0;q<OCB;++q){
    ACC bv = (cz==0) ? (ACC)bias[oc0+q] : (ACC)0;
    #pragma unroll
    for (int s=0;s<XT;++s) acc[q][s] = bv;
  }

  const int cbeg = cz * (CIN/NS);
  #pragma unroll 1
  for (int i=cbeg; i<cbeg + CIN/NS; ++i){
    const TIN* inc = in + (size_t)i*Din*Din*Din;
    const float* wci = w + ((size_t)oc0*CIN + i)*27;
    #pragma unroll
    for (int kd=0;kd<3;++kd){
      int z = zi0+kd;
      bool okz = (unsigned)z < (unsigned)Din;
      #pragma unroll
      for (int kh=0;kh<3;++kh){
        int y = yi0+kh;
        bool oky = (unsigned)y < (unsigned)Din;
        float wq[OCB][3];
        #pragma unroll
        for (int q=0;q<OCB;++q){
          const float* wr = wci + (size_t)q*CIN*27 + kd*9 + kh*3;
          #pragma unroll
          for (int kw=0;kw<3;++kw) wq[q][kw] = wr[kw];
        }
        if (okz && oky){
          const TIN* inr = inc + ((size_t)z*Din + y)*Din + xi0;
          ACC xv[SPAN];
          load_span<XT,STRIDE,TIN,ACC>(inr, xlo, xhi, xv);
          #pragma unroll
          for (int q=0;q<OCB;++q){
            #pragma unroll
            for (int kw=0;kw<3;++kw){
              ACC wv = (ACC)wq[q][kw];
              #pragma unroll
              for (int s=0;s<XT;++s)
                acc[q][s] = fma(wv, xv[s*STRIDE+kw], acc[q][s]);
            }
          }
        }
      }
    }
  }
  size_t vox = ((size_t)zo*Dout + yo)*Dout + xo0;
  #pragma unroll
  for (int q=0;q<OCB;++q)
    #pragma unroll
    for (int s=0;s<XT;++s)
      part[((size_t)(bz*NS+cz)*OC + (oc0+q))*n3 + vox + s] = acc[q][s];
}

// ================= vectorized deterministic reduces =================
template<int NS, int VEC, bool DOSILU, typename ACC, typename TOUT>
__global__ void r16_reduce(const ACC* __restrict__ part, TOUT* __restrict__ out, int total){
  int t0 = (blockIdx.x*256 + threadIdx.x)*VEC;
  if (t0 >= total) return;
  ACC a[VEC];
  #pragma unroll
  for (int v=0;v<VEC;++v) a[v] = part[t0+v];
  #pragma unroll
  for (int s=1;s<NS;++s){
    #pragma unroll
    for (int v=0;v<VEC;++v) a[v] += part[(size_t)s*total + t0+v];
  }
  #pragma unroll
  for (int v=0;v<VEC;++v){
    if (DOSILU){
      if (sizeof(ACC)==8) a[v] = (ACC)silu_d((double)a[v]);
      else                a[v] = (ACC)silu_f((float)a[v]);
    }
    out[t0+v] = (TOUT)a[v];
  }
}

template<int NS, int VEC, bool DOSILU, typename ACC, typename TOUT>
__global__ void r18_reduce_b(const ACC* __restrict__ part, TOUT* __restrict__ out, int total){
  int b = blockIdx.y;
  int t0 = (blockIdx.x*256 + threadIdx.x)*VEC;
  if (t0 >= total) return;
  const ACC* pb = part + (size_t)b*NS*total;
  ACC a[VEC];
  #pragma unroll
  for (int v=0;v<VEC;++v) a[v] = pb[t0+v];
  #pragma unroll
  for (int s=1;s<NS;++s){
    #pragma unroll
    for (int v=0;v<VEC;++v) a[v] += pb[(size_t)s*total + t0+v];
  }
  #pragma unroll
  for (int v=0;v<VEC;++v){
    if (DOSILU){
      if (sizeof(ACC)==8) a[v] = (ACC)silu_d((double)a[v]);
      else                a[v] = (ACC)silu_f((float)a[v]);
    }
    out[(size_t)b*total + t0+v] = (TOUT)a[v];
  }
}

// ================= quantconv absorbing NS=4 reduce (pair of batches) =================
__global__ void r19_quantconv4(const double* __restrict__ parts, const float* __restrict__ w,
                               const float* __restrict__ bias, double* __restrict__ seqd, int bbase){
  int t = blockIdx.x*256 + threadIdx.x;    // 2*16*4096 = 131072
  int n = t & 4095, e = (t>>12)&15, bp = t>>16;
  const double* p0 = parts + (size_t)(bp*4+0)*524288 + n;
  const double* p1 = parts + (size_t)(bp*4+1)*524288 + n;
  const double* p2 = parts + (size_t)(bp*4+2)*524288 + n;
  const double* p3 = parts + (size_t)(bp*4+3)*524288 + n;
  double acc = (double)bias[e];
  const float* we = w + e*128;
  for (int i=0;i<128;++i){
    size_t o = (size_t)i<<12;
    double val = ((p0[o]+p1[o])+p2[o])+p3[o];
    acc = fma(val, (double)we[i], acc);
  }
  seqd[((size_t)((bbase+bp)*NTOK+n))*ED + e] = acc;
}

// ================= batched postquant (all 4 batches) =================
__global__ void r19_postquant_all(const float* __restrict__ qpe, const float* __restrict__ w,
                                  const float* __restrict__ bias, float* __restrict__ pq_all){
  int t = blockIdx.x*256 + threadIdx.x;    // 4*128*4096 = 2097152
  int n = t & 4095, o = (t>>12)&127, b = t>>19;
  const float* qpeb = qpe + (size_t)b*65536;
  float acc = bias[o];
  const float* wo = w + o*16;
  #pragma unroll
  for (int e=0;e<16;++e) acc = fmaf(qpeb[((size_t)e<<12)+n], wo[e], acc);
  pq_all[t] = acc;
}

// ================= VQ (float64) =================
__global__ void r9_cnorm(const float* __restrict__ cb, double* __restrict__ cnormd){
  int k = blockIdx.x*256 + threadIdx.x;
  if (k >= KCB) return;
  const float* c = cb + (size_t)k*ED;
  double s = 0.0;
  #pragma unroll
  for (int e=0;e<ED;++e) s = fma((double)c[e], (double)c[e], s);
  cnormd[k] = s;
}

#define VQC 256
#define VQPARTS 32
template<int PARTS>
__global__ void r18_vq_partial(const double* __restrict__ seqd, const float* __restrict__ cb,
                               const double* __restrict__ cnormd,
                               double* __restrict__ pdist, int* __restrict__ pidx){
  __shared__ double scb[VQC*ED];
  __shared__ double snorm[VQC];
  const int part = blockIdx.y;
  const int tok0 = blockIdx.x*256 + threadIdx.x;   // 32 blocks -> 0..8191
  const int tok1 = tok0 + 8192;
  double s0[16], s1[16];
  const double* sr0 = seqd + (size_t)tok0*ED;
  const double* sr1 = seqd + (size_t)tok1*ED;
  #pragma unroll
  for (int e=0;e<16;++e){ s0[e] = sr0[e]; s1[e] = sr1[e]; }
  const int kbase = part * (KCB/PARTS);
  for (int u=threadIdx.x; u<VQC*ED; u+=256) scb[u] = (double)cb[(size_t)kbase*ED + u];
  for (int u=threadIdx.x; u<VQC; u+=256) snorm[u] = cnormd[kbase+u];
  __syncthreads();
  double best0 = 1.0e300, best1 = 1.0e300; int bi0 = 0, bi1 = 0;
  for (int kk=0; kk<VQC; ++kk){
    const double* cr = scb + kk*ED;
    double dot0 = 0.0, dot1 = 0.0;
    #pragma unroll
    for (int e=0;e<16;++e){
      double c = cr[e];
      dot0 = fma(s0[e], c, dot0);
      dot1 = fma(s1[e], c, dot1);
    }
    double nm = snorm[kk];
    double d0 = nm - 2.0*dot0;
    double d1 = nm - 2.0*dot1;
    if (d0 < best0){ best0 = d0; bi0 = kbase+kk; }
    if (d1 < best1){ best1 = d1; bi1 = kbase+kk; }
  }
  pdist[part*16384 + tok0] = best0;
  pidx [part*16384 + tok0] = bi0;
  pdist[part*16384 + tok1] = best1;
  pidx [part*16384 + tok1] = bi1;
}

template<int PARTS>
__global__ void r12_vq_merge(const double* __restrict__ pdist, const int* __restrict__ pidx,
                             const unsigned char* __restrict__ tnz, int* __restrict__ idxw,
                             float* __restrict__ out_idx, float* __restrict__ loss_slot){
  int tok = blockIdx.x*256 + threadIdx.x;
  if (tok == 0) *loss_slot = 0.f;
  double best = pdist[tok]; int bi = pidx[tok];
  #pragma unroll
  for (int p=1;p<PARTS;++p){
    double d2 = pdist[p*16384+tok];
    if (d2 < best){ best = d2; bi = pidx[p*16384+tok]; }
  }
  idxw[tok] = bi;
  out_idx[tok] = tnz[tok] ? (float)(bi+1) : 0.f;
}

__global__ void r9_commit(const double* __restrict__ seqd, const float* __restrict__ cb,
                          const int* __restrict__ idxw, const unsigned char* __restrict__ tnz,
                          float* __restrict__ loss_slot){
  int tok = blockIdx.x*256 + threadIdx.x;
  float v = 0.f;
  if (tnz[tok]){
    const float* c = cb + (size_t)idxw[tok]*ED;
    const double* s = seqd + (size_t)tok*ED;
    double acc = 0.0;
    #pragma unroll
    for (int e=0;e<ED;++e){ double d = (double)c[e]-s[e]; acc = fma(d,d,acc); }
    v = (float)(acc * (0.25/(16.0*16384.0)));
  }
  #pragma unroll
  for (int off=32; off; off>>=1) v += __shfl_down(v, off);
  if ((threadIdx.x & 63) == 0) atomicAdd(loss_slot, v);
}

__global__ void r9_gather_pos(const float* __restrict__ cb, const float* __restrict__ rep,
                              const int* __restrict__ idxw, const unsigned char* __restrict__ tnz,
                              const float* __restrict__ pos, float* __restrict__ qpe){
  int t = blockIdx.x*256 + threadIdx.x;   // B*16*4096
  int n = t & 4095, e = (t>>12)&15, b = t>>16;
  int tok = b*NTOK + n;
  float v = tnz[tok] ? cb[(size_t)idxw[tok]*ED + e] : rep[e];
  qpe[t] = v + pos[((size_t)e<<12) + n];
}

// ================= parity-fused + x-microtiled transposed conv =================
template<int CIN, int XT, bool DOSILU>
__global__ void r16_tconv(const float* __restrict__ in, const float* __restrict__ w,
                          const float* __restrict__ bias, float* __restrict__ out,
                          int Din){
  static_assert(XT==2, "XT must be 2");
  const int oc = blockIdx.y;
  const int nxt = Din / XT;
  const int t = blockIdx.x*256 + threadIdx.x;
  const int ux0 = (t % nxt)*XT;
  const int uy = (t/nxt)%Din, uz = t/(nxt*Din);
  const bool vx = ux0 > 0, vy = uy > 0, vz = uz > 0;
  const int DD = Din*Din, n3 = DD*Din;

  float b0 = bias[oc];
  float acc[8][XT];
  #pragma unroll
  for (int q=0;q<8;++q)
    #pragma unroll
    for (int s=0;s<XT;++s) acc[q][s] = b0;

  const float* p = in + ((size_t)uz*Din + uy)*Din + ux0;
  #pragma unroll 1
  for (int i=0;i<CIN;++i){
    float X[2][2][XT+1];
    #pragma unroll
    for (int za=0; za<2; ++za){
      #pragma unroll
      for (int ya=0; ya<2; ++ya){
        bool okzy = (za==1 || vz) && (ya==1 || vy);
        const float* pr = p + (za-1)*DD + (ya-1)*Din;
        if (okzy){
          f2v m = *(const f2v*)(pr);
          X[za][ya][1] = m.x; X[za][ya][2] = m.y;
          X[za][ya][0] = vx ? pr[-1] : 0.f;
        } else {
          X[za][ya][0] = 0.f; X[za][ya][1] = 0.f; X[za][ya][2] = 0.f;
        }
      }
    }
    const float* wi = w + ((size_t)(oc*CIN) + i)*27;
    #pragma unroll
    for (int kd=0;kd<3;++kd){
      #pragma unroll
      for (int kh=0;kh<3;++kh){
        #pragma unroll
        for (int kw=0;kw<3;++kw){
          const int pz = (kd==1) ? 1 : 0, py = (kh==1) ? 1 : 0, px = (kw==1) ? 1 : 0;
          const int za = (kd==0) ? 0 : 1, ya = (kh==0) ? 0 : 1, xa = (kw==0) ? 0 : 1;
          float wv = wi[kd*9+kh*3+kw];
          #pragma unroll
          for (int s=0;s<XT;++s)
            acc[pz*4+py*2+px][s] = fmaf(wv, X[za][ya][s+xa], acc[pz*4+py*2+px][s]);
        }
      }
    }
    p += n3;
  }
  if (DOSILU){
    #pragma unroll
    for (int q=0;q<8;++q)
      #pragma unroll
      for (int s=0;s<XT;++s) acc[q][s] = silu_f(acc[q][s]);
  }
  const int Dout = 2*Din;
  #pragma unroll
  for (int pz=0; pz<2; ++pz){
    #pragma unroll
    for (int py=0; py<2; ++py){
      float* row = out + (((size_t)oc*Dout + 2*uz+pz)*Dout + (2*uy+py))*Dout + 2*ux0;
      #pragma unroll
      for (int s=0;s<XT;++s){
        float2 v2 = make_float2(acc[pz*4+py*2+0][s], acc[pz*4+py*2+1][s]);
        *(float2*)(row + 2*s) = v2;
      }
    }
  }
}

// ================= batched tconv (NS=1): grid.z = batch =================
template<int CIN, int XT, bool DOSILU>
__global__ void r19_tconv_b(const float* __restrict__ in_all, size_t in_bstride,
                            const float* __restrict__ w, const float* __restrict__ bias,
                            float* __restrict__ out_all, size_t out_bstride, int Din){
  static_assert(XT==2, "XT must be 2");
  const int oc = blockIdx.y;
  const int bz = blockIdx.z;
  const float* in = in_all + (size_t)bz*in_bstride;
  float* out = out_all + (size_t)bz*out_bstride;
  const int nxt = Din / XT;
  const int t = blockIdx.x*256 + threadIdx.x;
  const int ux0 = (t % nxt)*XT;
  const int uy = (t/nxt)%Din, uz = t/(nxt*Din);
  const bool vx = ux0 > 0, vy = uy > 0, vz = uz > 0;
  const int DD = Din*Din, n3 = DD*Din;

  float b0 = bias[oc];
  float acc[8][XT];
  #pragma unroll
  for (int q=0;q<8;++q)
    #pragma unroll
    for (int s=0;s<XT;++s) acc[q][s] = b0;

  const float* p = in + ((size_t)uz*Din + uy)*Din + ux0;
  #pragma unroll 1
  for (int i=0;i<CIN;++i){
    float X[2][2][XT+1];
    #pragma unroll
    for (int za=0; za<2; ++za){
      #pragma unroll
      for (int ya=0; ya<2; ++ya){
        bool okzy = (za==1 || vz) && (ya==1 || vy);
        const float* pr = p + (za-1)*DD + (ya-1)*Din;
        if (okzy){
          f2v m = *(const f2v*)(pr);
          X[za][ya][1] = m.x; X[za][ya][2] = m.y;
          X[za][ya][0] = vx ? pr[-1] : 0.f;
        } else {
          X[za][ya][0] = 0.f; X[za][ya][1] = 0.f; X[za][ya][2] = 0.f;
        }
      }
    }
    const float* wi = w + ((size_t)(oc*CIN) + i)*27;
    #pragma unroll
    for (int kd=0;kd<3;++kd){
      #pragma unroll
      for (int kh=0;kh<3;++kh){
        #pragma unroll
        for (int kw=0;kw<3;++kw){
          const int pz = (kd==1) ? 1 : 0, py = (kh==1) ? 1 : 0, px = (kw==1) ? 1 : 0;
          const int za = (kd==0) ? 0 : 1, ya = (kh==0) ? 0 : 1, xa = (kw==0) ? 0 : 1;
          float wv = wi[kd*9+kh*3+kw];
          #pragma unroll
          for (int s=0;s<XT;++s)
            acc[pz*4+py*2+px][s] = fmaf(wv, X[za][ya][s+xa], acc[pz*4+py*2+px][s]);
        }
      }
    }
    p += n3;
  }
  if (DOSILU){
    #pragma unroll
    for (int q=0;q<8;++q)
      #pragma unroll
      for (int s=0;s<XT;++s) acc[q][s] = silu_f(acc[q][s]);
  }
  const int Dout = 2*Din;
  #pragma unroll
  for (int pz=0; pz<2; ++pz){
    #pragma unroll
    for (int py=0; py<2; ++py){
      float* row = out + (((size_t)oc*Dout + 2*uz+pz)*Dout + (2*uy+py))*Dout + 2*ux0;
      #pragma unroll
      for (int s=0;s<XT;++s){
        float2 v2 = make_float2(acc[pz*4+py*2+0][s], acc[pz*4+py*2+1][s]);
        *(float2*)(row + 2*s) = v2;
      }
    }
  }
}

// diagnostic if workspace too small: out[0] = 9e6 + ws_MiB
__global__ void r9_diag_ws(float* out0, float v){
  if (threadIdx.x == 0 && blockIdx.x == 0) out0[0] = v;
}

// ================= launch =================
extern "C" void kernel_launch(void* const* d_in, const int* in_sizes, int n_in,
                              void* d_out, int out_size, void* d_ws, size_t ws_size,
                              hipStream_t stream){
  const unsigned char* x = (const unsigned char*)d_in[0];
  const float* enc_in_w  = (const float*)d_in[1];
  const float* enc_in_b  = (const float*)d_in[2];
  const float* enc_d1_w  = (const float*)d_in[3];
  const float* enc_d1_b  = (const float*)d_in[4];
  const float* enc_d2_w  = (const float*)d_in[5];
  const float* enc_d2_b  = (const float*)d_in[6];
  const float* enc_out_w = (const float*)d_in[7];
  const float* enc_out_b = (const float*)d_in[8];
  const float* quant_w   = (const float*)d_in[9];
  const float* quant_b   = (const float*)d_in[10];
  const float* codebook  = (const float*)d_in[11];
  const float* rep_tok   = (const float*)d_in[12];
  const float* pos_emb   = (const float*)d_in[13];
  const float* pq_w      = (const float*)d_in[14];
  const float* pq_b      = (const float*)d_in[15];
  const float* dec_in_w  = (const float*)d_in[16];
  const float* dec_in_b  = (const float*)d_in[17];
  const float* dec_u1_w  = (const float*)d_in[18];
  const float* dec_u1_b  = (const float*)d_in[19];
  const float* dec_u2_w  = (const float*)d_in[20];
  const float* dec_u2_b  = (const float*)d_in[21];
  const float* dec_out_w = (const float*)d_in[22];
  const float* dec_out_b = (const float*)d_in[23];

  float* out = (float*)d_out;
  const size_t OFF_RECON = 0;
  const size_t OFF_MC    = 8388608;
  const size_t OFF_LOSS  = 16777216;
  const size_t OFF_IDX   = 16777217;

  // ---- workspace layout (bytes); total 55.9 MiB, unchanged ----
  char* wsb = (char*)d_ws;
  float*  Sbig  = (float*) (wsb + 0);          // 33,554,432 : h1_b / u2_out / partials / VQ scratch
  double* seqd  = (double*)(wsb + 54525952);   //  2,097,152
  double* cnormd= (double*)(wsb + 56623104);   //     65,536
  int*    idxw  = (int*)   (wsb + 57475072);   //     65,536
  unsigned char* tnz = (unsigned char*)(wsb + 57540608); // 16,384
  float*  qpe   = (float*) (wsb + 57556992);   //  1,048,576
  int*    dflag = (int*)   (wsb + 58605568);   //         64
  const size_t WS_NEEDED = 58605632;

  // scratch aliases (all in ws; dead-window reuse):
  double* scr_d  = (double*)wsb;                    // f64 partials (Sbig), 32 MiB
  float*  scr_f  = (float*)wsb;                     // f32 partials (Sbig), 32 MiB
  float*  h2w    = (float*)(wsb + 33554432);        // h2 pair (2 x 8 MiB)
  double* h3w    = (double*)(wsb + 33554432);       // h3 pair (2 x 4 MiB f64)
  float*  pq_all = (float*)(wsb + 33554432);        // [4][128][4096] f32, 8 MiB
  float*  dD_all = (float*)(wsb + 41943040);        // [4][128][4096] f32, 8 MiB
  float*  scr_f2 = (float*)(wsb + 33554432);        // dec_out partials, 16 MiB
  double* pdist  = (double*)wsb;                    // VQ partial dists (Sbig)
  int*    pidx   = (int*)(wsb + VQPARTS*16384*8);   // VQ partial idx
  float*  u1_all = out + OFF_RECON;                 // [4][64][32768] f32 = 32 MiB (recon region; write-then-consume)

  dim3 blk(256);

  if (ws_size < WS_NEEDED){
    r9_diag_ws<<<dim3(1), dim3(64), 0, stream>>>(out + OFF_RECON,
        9.0e6f + (float)(ws_size >> 20));
    return;
  }

  // 0) input dtype probe (block-reduced flags)
  r9_probe_zero<<<dim3(1), dim3(64), 0, stream>>>(dflag);
  r17_probe<<<dim3(256), blk, 0, stream>>>(x, dflag);

  // 1) pack + token-nonzero mask
  r9_pack_mc<<<dim3(4096), blk, 0, stream>>>(x, out + OFF_MC, dflag);
  r9_token_nz<<<dim3(256), dim3(64), 0, stream>>>(out + OFF_MC, tnz);

  // 2) encoder, pair-wise (weight-hoisted convs; slice-major batched parts)
  for (int p = 0; p < 2; ++p){
    for (int bp = 0; bp < 2; ++bp){
      int b = 2*p + bp;
      const float* mcb = out + OFF_MC + (size_t)b*8*262144;
      r22_conv3x3<8,8,4,1,true,float,float,double>  <<<dim3(256,4,1), blk, 0, stream>>>(mcb,  enc_in_w, enc_in_b, Sbig, 64, 64);
      r22_conv3x3<32,4,4,2,true,float,float,double> <<<dim3(32,16,1), blk, 0, stream>>>(Sbig, enc_d1_w, enc_d1_b, h2w + (size_t)bp*2097152, 64, 32);
    }
    // enc_d2 pair: NS=4, slice-major grid (8,32,4) = 1024 blocks; partials 32 MiB f64 in Sbig
    r22_conv_part_b<64,4,4,4,2,float,double><<<dim3(8,32,4), blk, 0, stream>>>(h2w, 2097152, enc_d2_w, enc_d2_b, scr_d, 32, 16);
    r18_reduce_b<4,2,true,double,double><<<dim3(1024,2), blk, 0, stream>>>(scr_d, h3w, 524288);
    // enc_out pair: NS=4, slice-major grid (8,32,4) = 1024 blocks; partials back in Sbig
    r22_conv_part_b<128,4,4,4,1,double,double><<<dim3(8,32,4), blk, 0, stream>>>(h3w, 524288, enc_out_w, enc_out_b, scr_d, 16, 16);
    // quantconv absorbs the NS=4 reduce
    r19_quantconv4<<<dim3(512), blk, 0, stream>>>(scr_d, quant_w, quant_b, seqd, 2*p);
  }

  // 3) VQ (fp64): 32 partitions, 2-token-tiled -> grid (32,32) = 1024 blocks.
  r9_cnorm<<<dim3(32), blk, 0, stream>>>(codebook, cnormd);
  r18_vq_partial<VQPARTS><<<dim3(32,VQPARTS), blk, 0, stream>>>(seqd, codebook, cnormd, pdist, pidx);
  r12_vq_merge<VQPARTS><<<dim3(64), blk, 0, stream>>>(pdist, pidx, tnz, idxw, out + OFF_IDX, out + OFF_LOSS);
  r9_commit<<<dim3(64), blk, 0, stream>>>(seqd, codebook, idxw, tnz, out + OFF_LOSS);

  // 4) decoder: batched front half, per-batch back half
  r9_gather_pos<<<dim3(1024), blk, 0, stream>>>(codebook, rep_tok, idxw, tnz, pos_emb, qpe);
  r19_postquant_all<<<dim3(8192), blk, 0, stream>>>(qpe, pq_w, pq_b, pq_all);
  // dec_in batched: NS=4, slice-major grid (16,32,4) = 2048 blocks; partials 32 MiB f32 in Sbig
  r22_conv_part_b<128,4,4,4,1,float,float><<<dim3(16,32,4), blk, 0, stream>>>(pq_all, 524288, dec_in_w, dec_in_b, scr_f, 16, 16);
  r18_reduce_b<4,4,true,float,float><<<dim3(512,4), blk, 0, stream>>>(scr_f, dD_all, 524288);
  // dec_u1 batched NS=1: grid (8,64,4) = 2048 blocks; silu inline; out -> u1_all (write-only)
  r19_tconv_b<128,2,true><<<dim3(8,64,4), blk, 0, stream>>>(dD_all, 524288, dec_u1_w, dec_u1_b, u1_all, 2097152, 16);
  // per-batch back half
  for (int b = 0; b < BB; ++b){
    float* reconb = out + OFF_RECON + (size_t)b*2097152;
    r16_tconv<64,2,true> <<<dim3(64,32,1), blk, 0, stream>>>(u1_all + (size_t)b*2097152, dec_u2_w, dec_u2_b, Sbig, 32);
    r22_conv_part<32,8,4,2,1,float,float><<<dim3(256,1,2), blk, 0, stream>>>(Sbig, dec_out_w, dec_out_b, scr_f2, 64, 64);
    r16_reduce<2,4,false,float,float><<<dim3(2048), blk, 0, stream>>>(scr_f2, reconb, 2097152);
  }
}